// Round 8
// baseline (520.836 us; speedup 1.0000x reference)
//
#include <hip/hip_runtime.h>
#include <hip/hip_fp16.h>
#include <math.h>

#define HP8 8     // halves per packed alpha row (6 heads + 2 pad)
#define NEG_SLOPE 0.2f
#define TILE 16   // nodes per k_node_prep block
#define BKB 7     // bucket = dst >> 7  (128 nodes per bucket)

// ==================== CSR build (graph identical for both layers) ==========

__global__ __launch_bounds__(256) void k_init_deg(int* __restrict__ deg, int N)
{
    int i = blockIdx.x * blockDim.x + threadIdx.x;
    if (i < N) deg[i] = 1;                    // self-loop
}

__global__ __launch_bounds__(256) void k_count(const int* __restrict__ g, int E,
                                               int* __restrict__ deg)
{
    int e = blockIdx.x * blockDim.x + threadIdx.x;
    if (e < E) atomicAdd(&deg[g[E + e]], 1);
}

// Two-level scan: per-1024-chunk sums, scan partials, then emit offsets.
__global__ __launch_bounds__(256) void k_block_sum(
    const int* __restrict__ deg, int* __restrict__ psum, int N)
{
    __shared__ int wsum[4];
    const int t = threadIdx.x, lane = t & 63, w = t >> 6;
    const int i0 = blockIdx.x * 1024 + t * 4;
    int s = 0;
    #pragma unroll
    for (int q = 0; q < 4; ++q) if (i0 + q < N) s += deg[i0 + q];
    #pragma unroll
    for (int off = 32; off > 0; off >>= 1) s += __shfl_xor(s, off);
    if (lane == 0) wsum[w] = s;
    __syncthreads();
    if (t == 0) psum[blockIdx.x] = wsum[0] + wsum[1] + wsum[2] + wsum[3];
}

__global__ void k_scan_partials(const int* __restrict__ psum,
                                int* __restrict__ poff, int NB)
{
    int lane = threadIdx.x;                   // 64 threads
    if (NB <= 64) {
        int v = (lane < NB) ? psum[lane] : 0;
        int incl = v;
        #pragma unroll
        for (int off = 1; off < 64; off <<= 1) {
            int u = __shfl_up(incl, off);
            if (lane >= off) incl += u;
        }
        if (lane < NB) poff[lane] = incl - v;
    } else if (lane == 0) {
        int run = 0;
        for (int b = 0; b < NB; ++b) { poff[b] = run; run += psum[b]; }
    }
}

__global__ __launch_bounds__(256) void k_emit(
    const int* __restrict__ deg, const int* __restrict__ poff,
    int* __restrict__ rowptr, int* __restrict__ adj, int N)
{
    __shared__ int wsum[4];
    const int t = threadIdx.x, lane = t & 63, w = t >> 6;
    const int i0 = blockIdx.x * 1024 + t * 4;
    int d[4];
    #pragma unroll
    for (int q = 0; q < 4; ++q) d[q] = (i0 + q < N) ? deg[i0 + q] : 0;
    int ts = d[0] + d[1] + d[2] + d[3];
    int incl = ts;
    #pragma unroll
    for (int off = 1; off < 64; off <<= 1) {
        int u = __shfl_up(incl, off);
        if (lane >= off) incl += u;
    }
    if (lane == 63) wsum[w] = incl;
    __syncthreads();
    int base = poff[blockIdx.x];
    for (int q = 0; q < w; ++q) base += wsum[q];
    int excl = base + (incl - ts);
    #pragma unroll
    for (int q = 0; q < 4; ++q) {
        int i = i0 + q;
        if (i < N) {
            rowptr[i] = excl;
            adj[excl] = i;                    // self-loop first
            excl += d[q];
        }
    }
}

// ---- binned two-phase edge scatter ----
__global__ __launch_bounds__(128) void k_bucket_cnt(
    const int* __restrict__ deg, int* __restrict__ bcnt, int N)
{
    __shared__ int w2[2];
    const int b = blockIdx.x, t = threadIdx.x;
    const int i = b * 128 + t;
    int v = (i < N) ? deg[i] - 1 : 0;         // edges only (no self-loop)
    #pragma unroll
    for (int o = 32; o > 0; o >>= 1) v += __shfl_xor(v, o);
    if ((t & 63) == 0) w2[t >> 6] = v;
    __syncthreads();
    if (t == 0) bcnt[b] = w2[0] + w2[1];
}

__global__ __launch_bounds__(1024) void k_bucket_scan(
    const int* __restrict__ bcnt, int* __restrict__ boff,
    int* __restrict__ bcur, int NBK)
{
    __shared__ int s[1024];
    const int t = threadIdx.x;
    if (t < NBK) s[t] = bcnt[t];
    __syncthreads();
    if (t == 0) {
        int run = 0;
        for (int b = 0; b < NBK; ++b) { int v = s[b]; s[b] = run; run += v; }
        boff[NBK] = run;
    }
    __syncthreads();
    if (t < NBK) { boff[t] = s[t]; bcur[t] = s[t]; }
}

// pass 1: bin (src,dst) pairs into contiguous per-bucket regions.
__global__ __launch_bounds__(256) void k_bin(
    const int* __restrict__ g, int E, int* __restrict__ bcur,
    int2* __restrict__ pairs)
{
    int e = blockIdx.x * blockDim.x + threadIdx.x;
    if (e >= E) return;
    int s = g[e], d = g[E + e];
    int pos = atomicAdd(&bcur[d >> BKB], 1);
    pairs[pos] = make_int2(s, d);
}

// pass 2: one block per bucket; LDS cursors; writes land in a ~9 KB window.
__global__ __launch_bounds__(256) void k_scatter2(
    const int2* __restrict__ pairs, const int* __restrict__ boff,
    const int* __restrict__ rowptr, int* __restrict__ adj, int N)
{
    __shared__ int cur[128];
    const int b = blockIdx.x, t = threadIdx.x;
    if (t < 128) {
        int node = b * 128 + t;
        cur[t] = (node < N) ? rowptr[node] + 1 : 0;   // after self-loop
    }
    __syncthreads();
    const int lo = boff[b], hi = boff[b + 1];
    for (int i = lo + t; i < hi; i += 256) {
        int2 p = pairs[i];
        int pos = atomicAdd(&cur[p.y & 127], 1);
        adj[pos] = p.x;
    }
}

// ==================== setup: alpha-weight folding + MLP collapse ============
__global__ void k_setup(
    const float* __restrict__ W1, const float* __restrict__ as1,
    const float* __restrict__ ad1,
    const float* __restrict__ W2, const float* __restrict__ as2,
    const float* __restrict__ ad2,
    const float* __restrict__ lw1, const float* __restrict__ lb1,
    const float* __restrict__ lw2, const float* __restrict__ lb2,
    float* __restrict__ wsd1, float* __restrict__ wsd2,
    float* __restrict__ weff)
{
    int t = threadIdx.x;                      // 832 threads
    if (t < 768) {
        int layer = (t >= 384);
        int r = t - layer * 384;              // r in [0,384)
        int k = r / 12, j = r - k * 12;
        const float* W = layer ? W2 : W1;
        const float* a = (j < 6) ? (layer ? as2 : as1) : (layer ? ad2 : ad1);
        int h = (j < 6) ? j : j - 6;
        float acc = 0.f;
        #pragma unroll
        for (int c = 0; c < 32; ++c)
            acc = fmaf(W[k * 192 + h * 32 + c], a[h * 32 + c], acc);
        (layer ? wsd2 : wsd1)[k * 12 + j] = acc;
    } else {
        int i = t - 768;                      // 0..63
        float acc = 0.f;
        for (int o = 0; o < 64; ++o) acc += lw1[i * 64 + o] * lw2[o];
        weff[i] = acc;
        if (i == 0) {
            float b = lb2[0];
            for (int o = 0; o < 64; ++o) b += lb1[o] * lw2[o];
            weff[64] = b;
        }
    }
}

// ==================== node prep =============================================
// One block per TILE nodes. Thread t owns output column t = h*32+c.
// xhp layout: [n][c][h] halves -> 12 B per (n,c), row = 384 B.
// asrcp/adstp: [n][h] fp16, row stride HP8 halves (16 B).
__global__ __launch_bounds__(192) void k_node_prep(
    const float* __restrict__ xsrc, const int* __restrict__ gidx,
    const float* __restrict__ W, const float* __restrict__ wsd,
    __half* __restrict__ xhp, __half* __restrict__ asrcp,
    __half* __restrict__ adstp, int N)
{
    __shared__ float xs[TILE * 33];           // stride 33: bank-conflict-free
    __shared__ int   rows[TILE];
    __shared__ float wsd_s[32 * 12];
    const int t = threadIdx.x;

    float wcol[32];
    #pragma unroll
    for (int k = 0; k < 32; ++k) wcol[k] = W[k * 192 + t];
    for (int i = t; i < 32 * 12; i += 192) wsd_s[i] = wsd[i];

    const int h = t >> 5;
    const int c = t & 31;
    const int n0 = blockIdx.x * TILE;
    if (t < TILE) {
        int n = n0 + t;
        rows[t] = (n < N) ? (gidx ? gidx[n] : n) : -1;
    }
    __syncthreads();
    if (t < TILE * 8) {                       // 16 rows x 8 float4
        int m = t >> 3, q = t & 7;
        int r = rows[m];
        float4 v = (r >= 0) ? *(const float4*)(xsrc + (size_t)r * 32 + q * 4)
                            : make_float4(0.f, 0.f, 0.f, 0.f);
        float* dst = xs + m * 33 + q * 4;
        dst[0] = v.x; dst[1] = v.y; dst[2] = v.z; dst[3] = v.w;
    }
    __syncthreads();

    const int nvalid = min(TILE, N - n0);
    const int xoff = c * 6 + h;               // channel-major packed half index
    #pragma unroll 4
    for (int m = 0; m < TILE; ++m) {
        const float* xr = xs + m * 33;
        float a = 0.f;
        #pragma unroll
        for (int k = 0; k < 32; ++k) a = fmaf(xr[k], wcol[k], a);
        if (m < nvalid)
            xhp[(size_t)(n0 + m) * 192 + xoff] = __float2half(a);
    }

    // alpha: thread t -> (node m = t/12, j = t%12); 16*12 = 192 = blockDim.
    {
        int m = t / 12, j = t - m * 12;
        if (m < nvalid) {
            const float* xr = xs + m * 33;
            float a = 0.f;
            #pragma unroll
            for (int k = 0; k < 32; ++k) a = fmaf(xr[k], wsd_s[k * 12 + j], a);
            if (j < 6) asrcp[(size_t)(n0 + m) * HP8 + j] = __float2half(a);
            else       adstp[(size_t)(n0 + m) * HP8 + (j - 6)] = __float2half(a);
        }
    }
}

// ==================== fused softmax + aggregation ===========================
// One 64-lane wave per node. lane = channel c in both halves; the two halves
// process EVEN/ODD edges respectively (accumulators merged at the end).
// Per 32-edge chunk: lane el computes edge el's 6 exp-weights, packs a 16 B
// record (s_byteoff, w01, w23, w45 as half2) into LDS; gather loop reads the
// record with one broadcast ds_read_b128, ONE dwordx3 load (6 halves at
// [n][c][h]) and 3 hfma2.  No max-subtraction (scores are O(0.1)).
template<int FUSE>
__global__ __launch_bounds__(256) void k_gat_node(
    const int* __restrict__ rowptr, const int* __restrict__ deg,
    const int* __restrict__ adj,
    const __half* __restrict__ asrcp, const __half* __restrict__ adstp,
    const __half* __restrict__ xhp, const float* __restrict__ bias,
    float* __restrict__ y, int N,
    const int* __restrict__ user, const float* __restrict__ u_table,
    const float* __restrict__ weff, float* __restrict__ out)
{
    __shared__ float4 st[4][32];
    const int wv = threadIdx.x >> 6;
    const int n = blockIdx.x * 4 + wv;
    if (n >= N) return;
    const int lane = threadIdx.x & 63;
    const int half = lane >> 5;
    const int c = lane & 31;
    const int el = lane & 31;

    // dst alphas (uniform per node)
    const __half2 adA = *(const __half2*)(adstp + (size_t)n * HP8 + 0);
    const __half2 adB = *(const __half2*)(adstp + (size_t)n * HP8 + 2);
    const __half2 adC = *(const __half2*)(adstp + (size_t)n * HP8 + 4);
    const float ad0 = __low2float(adA), ad1 = __high2float(adA);
    const float ad2 = __low2float(adB), ad3 = __high2float(adB);
    const float ad4 = __low2float(adC), ad5 = __high2float(adC);

    const int start = rowptr[n];
    const int dg = deg[n];
    const char* xcb = (const char*)xhp + c * 12;   // channel base

    __half2 acc0 = __float2half2_rn(0.f);
    __half2 acc1 = __float2half2_rn(0.f);
    __half2 acc2 = __float2half2_rn(0.f);
    float dl0 = 0.f, dl1 = 0.f, dl2 = 0.f, dl3 = 0.f, dl4 = 0.f, dl5 = 0.f;

    for (int base = 0; base < dg; base += 32) {
        const int rem = dg - base;
        const bool valid = el < rem;
        const int s = valid ? adj[start + base + el] : 0;
        // src alphas: one float4 = 8 halves (6 used)
        const float4 av = *(const float4*)(asrcp + (size_t)s * HP8);
        const __half2 aA = *(const __half2*)&av.x;
        const __half2 aB = *(const __half2*)&av.y;
        const __half2 aC = *(const __half2*)&av.z;
        float v0 = __low2float(aA) + ad0, v1 = __high2float(aA) + ad1;
        float v2 = __low2float(aB) + ad2, v3 = __high2float(aB) + ad3;
        float v4 = __low2float(aC) + ad4, v5 = __high2float(aC) + ad5;
        v0 = fmaxf(v0, NEG_SLOPE * v0); v1 = fmaxf(v1, NEG_SLOPE * v1);
        v2 = fmaxf(v2, NEG_SLOPE * v2); v3 = fmaxf(v3, NEG_SLOPE * v3);
        v4 = fmaxf(v4, NEG_SLOPE * v4); v5 = fmaxf(v5, NEG_SLOPE * v5);
        const float w0 = valid ? __expf(v0) : 0.f;
        const float w1 = valid ? __expf(v1) : 0.f;
        const float w2 = valid ? __expf(v2) : 0.f;
        const float w3 = valid ? __expf(v3) : 0.f;
        const float w4 = valid ? __expf(v4) : 0.f;
        const float w5 = valid ? __expf(v5) : 0.f;
        dl0 += w0; dl1 += w1; dl2 += w2; dl3 += w3; dl4 += w4; dl5 += w5;
        float4 rec;
        rec.x = __int_as_float(s * 384);
        const __half2 w01 = __floats2half2_rn(w0, w1);
        const __half2 w23 = __floats2half2_rn(w2, w3);
        const __half2 w45 = __floats2half2_rn(w4, w5);
        rec.y = *(const float*)&w01;
        rec.z = *(const float*)&w23;
        rec.w = *(const float*)&w45;
        if (lane < 32) st[wv][el] = rec;      // half 0 writes records

        // gather: halves take even/odd edges; pad records are zero-weight
        const int cnt = min(32, rem);
        int npairs = (cnt + 1) >> 1;
        npairs = (npairs + 1) & ~1;           // even trip, slots < 32 all valid
        for (int i = 0; i < npairs; i += 2) {
            #pragma unroll
            for (int q = 0; q < 2; ++q) {
                const float4 r = st[wv][2 * (i + q) + half];
                const char* p = xcb + __float_as_int(r.x);
                const uint3 dv = *(const uint3*)p;        // 6 halves (12 B)
                acc0 = __hfma2(*(const __half2*)&r.y, *(const __half2*)&dv.x, acc0);
                acc1 = __hfma2(*(const __half2*)&r.z, *(const __half2*)&dv.y, acc1);
                acc2 = __hfma2(*(const __half2*)&r.w, *(const __half2*)&dv.z, acc2);
            }
        }
    }

    // combine halves (even/odd edge partial sums)
    float s0 = __low2float(acc0), s1 = __high2float(acc0);
    float s2 = __low2float(acc1), s3 = __high2float(acc1);
    float s4 = __low2float(acc2), s5 = __high2float(acc2);
    s0 += __shfl_xor(s0, 32); s1 += __shfl_xor(s1, 32);
    s2 += __shfl_xor(s2, 32); s3 += __shfl_xor(s3, 32);
    s4 += __shfl_xor(s4, 32); s5 += __shfl_xor(s5, 32);
    // reduce denominators over the 32 edge-slots (halves identical)
    #pragma unroll
    for (int o = 1; o <= 16; o <<= 1) {
        dl0 += __shfl_xor(dl0, o); dl1 += __shfl_xor(dl1, o);
        dl2 += __shfl_xor(dl2, o); dl3 += __shfl_xor(dl3, o);
        dl4 += __shfl_xor(dl4, o); dl5 += __shfl_xor(dl5, o);
    }
    const float r = s0 / (dl0 + 1e-16f) + s1 / (dl1 + 1e-16f)
                  + s2 / (dl2 + 1e-16f) + s3 / (dl3 + 1e-16f)
                  + s4 / (dl4 + 1e-16f) + s5 / (dl5 + 1e-16f);
    const float yv = r * (1.f / 6.f) + bias[c];

    if (FUSE == 0) {
        if (half == 0) y[(size_t)n * 32 + c] = yv;
    } else {
        // out[n] = sigmoid([u_emb | y].weff + b): half0 lanes dot the y part,
        // half1 lanes dot the u part, then full-wave reduce.
        float p = (half == 0) ? yv * weff[32 + c]
                              : u_table[(size_t)user[n] * 32 + c] * weff[c];
        #pragma unroll
        for (int o = 32; o > 0; o >>= 1) p += __shfl_xor(p, o);
        if (lane == 0) out[n] = 1.f / (1.f + __expf(-(p + weff[64])));
    }
}

// ==================== launch ================================================

extern "C" void kernel_launch(void* const* d_in, const int* in_sizes, int n_in,
                              void* d_out, int out_size, void* d_ws, size_t ws_size,
                              hipStream_t stream)
{
    const int*   user    = (const int*)  d_in[0];
    const int*   item    = (const int*)  d_in[1];
    const int*   graph   = (const int*)  d_in[2];
    const float* u_table = (const float*)d_in[3];
    const float* i_table = (const float*)d_in[4];
    const float* W1      = (const float*)d_in[5];
    const float* a_src1  = (const float*)d_in[6];
    const float* a_dst1  = (const float*)d_in[7];
    const float* b1      = (const float*)d_in[8];
    const float* W2      = (const float*)d_in[9];
    const float* a_src2  = (const float*)d_in[10];
    const float* a_dst2  = (const float*)d_in[11];
    const float* b2      = (const float*)d_in[12];
    const float* lw1     = (const float*)d_in[13];
    const float* lb1     = (const float*)d_in[14];
    const float* lw2     = (const float*)d_in[15];
    const float* lb2     = (const float*)d_in[16];

    const int B  = in_sizes[0];
    const int N  = B;
    const int E  = in_sizes[2] / 2;
    const int Et = E + N;
    const int NB = (N + 1023) / 1024;
    const int NBK = (N + 127) / 128;          // buckets of 128 nodes

    float* ws = (float*)d_ws;
    size_t off = 0;
    __half* xhp   = (__half*)(ws + off); off += (size_t)N * 96;  // N*192 halves
    __half* asrcp = (__half*)(ws + off); off += (size_t)N * 4;   // N*8 halves
    __half* adstp = (__half*)(ws + off); off += (size_t)N * 4;
    float* y1     = ws + off; off += (size_t)N * 32;
    float* weff   = ws + off; off += 128;
    float* wsd1   = ws + off; off += 384;
    float* wsd2   = ws + off; off += 384;
    int*   deg    = (int*)(ws + off); off += N;
    int*   rowptr = (int*)(ws + off); off += N;
    int*   psum   = (int*)(ws + off); off += NB + 1;
    int*   poff   = (int*)(ws + off); off += NB + 1;
    int*   bcnt   = (int*)(ws + off); off += NBK + 1;
    int*   boff   = (int*)(ws + off); off += NBK + 1;
    int*   bcur   = (int*)(ws + off); off += NBK + 1;
    int*   adj    = (int*)(ws + off); off += Et + 2;
    off = (off + 1) & ~(size_t)1;             // align int2
    int2*  pairs  = (int2*)(ws + off); off += (size_t)E * 2;

    const int egrid = (E + 255) / 256;
    const int ngrid = (N + 255) / 256;
    const int ggrid = (N + 3) / 4;
    const int pgrid = (N + TILE - 1) / TILE;

    // ---- CSR build (once; graph shared by both layers) ----
    hipLaunchKernelGGL(k_init_deg, dim3(ngrid), dim3(256), 0, stream, deg, N);
    hipLaunchKernelGGL(k_count,    dim3(egrid), dim3(256), 0, stream, graph, E, deg);
    hipLaunchKernelGGL(k_block_sum, dim3(NB), dim3(256), 0, stream, deg, psum, N);
    hipLaunchKernelGGL(k_scan_partials, dim3(1), dim3(64), 0, stream, psum, poff, NB);
    hipLaunchKernelGGL(k_emit, dim3(NB), dim3(256), 0, stream,
        deg, poff, rowptr, adj, N);
    hipLaunchKernelGGL(k_bucket_cnt, dim3(NBK), dim3(128), 0, stream, deg, bcnt, N);
    hipLaunchKernelGGL(k_bucket_scan, dim3(1), dim3(1024), 0, stream,
        bcnt, boff, bcur, NBK);
    hipLaunchKernelGGL(k_bin, dim3(egrid), dim3(256), 0, stream,
        graph, E, bcur, pairs);
    hipLaunchKernelGGL(k_scatter2, dim3(NBK), dim3(256), 0, stream,
        pairs, boff, rowptr, adj, N);

    // ---- setup: fold alpha vectors into W (both layers) + MLP collapse ----
    hipLaunchKernelGGL(k_setup, dim3(1), dim3(832), 0, stream,
        W1, a_src1, a_dst1, W2, a_src2, a_dst2,
        lw1, lb1, lw2, lb2, wsd1, wsd2, weff);

    // ---- GAT layer 1 (input: i_table gathered by item) ----
    hipLaunchKernelGGL(k_node_prep, dim3(pgrid), dim3(192), 0, stream,
        i_table, item, W1, wsd1, xhp, asrcp, adstp, N);
    hipLaunchKernelGGL(k_gat_node<0>, dim3(ggrid), dim3(256), 0, stream,
        rowptr, deg, adj, asrcp, adstp, xhp, b1, y1, N,
        (const int*)nullptr, (const float*)nullptr,
        (const float*)nullptr, (float*)nullptr);

    // ---- GAT layer 2 (input: y1) + fused MLP head + sigmoid ----
    hipLaunchKernelGGL(k_node_prep, dim3(pgrid), dim3(192), 0, stream,
        y1, (const int*)nullptr, W2, wsd2, xhp, asrcp, adstp, N);
    hipLaunchKernelGGL(k_gat_node<1>, dim3(ggrid), dim3(256), 0, stream,
        rowptr, deg, adj, asrcp, adstp, xhp, b2, (float*)nullptr, N,
        user, u_table, weff, (float*)d_out);
}

// Round 9
// 279.759 us; speedup vs baseline: 1.8617x; 1.8617x over previous
//
#include <hip/hip_runtime.h>
#include <hip/hip_fp16.h>
#include <math.h>

#define HP8 8     // halves per packed alpha row (6 heads + 2 pad)
#define NEG_SLOPE 0.2f
#define TILE 16   // nodes per k_node_prep block
#define BKB2 8    // bucket = dst >> 8  (256 nodes per bucket)
#define CHUNK 16384

// ==================== CSR build (graph identical for both layers) ==========

__global__ __launch_bounds__(256) void k_init_deg(int* __restrict__ deg, int N,
                                                  int* __restrict__ bcnt, int NBK)
{
    int i = blockIdx.x * blockDim.x + threadIdx.x;
    if (i < N) deg[i] = 1;                    // self-loop
    if (i < NBK) bcnt[i] = 0;
}

__global__ __launch_bounds__(256) void k_count(const int* __restrict__ g, int E,
                                               int* __restrict__ deg)
{
    int e = blockIdx.x * blockDim.x + threadIdx.x;
    if (e < E) atomicAdd(&deg[g[E + e]], 1);
}

// Two-level scan: per-1024-chunk sums, scan partials, then emit offsets.
__global__ __launch_bounds__(256) void k_block_sum(
    const int* __restrict__ deg, int* __restrict__ psum, int N)
{
    __shared__ int wsum[4];
    const int t = threadIdx.x, lane = t & 63, w = t >> 6;
    const int i0 = blockIdx.x * 1024 + t * 4;
    int s = 0;
    #pragma unroll
    for (int q = 0; q < 4; ++q) if (i0 + q < N) s += deg[i0 + q];
    #pragma unroll
    for (int off = 32; off > 0; off >>= 1) s += __shfl_xor(s, off);
    if (lane == 0) wsum[w] = s;
    __syncthreads();
    if (t == 0) psum[blockIdx.x] = wsum[0] + wsum[1] + wsum[2] + wsum[3];
}

__global__ void k_scan_partials(const int* __restrict__ psum,
                                int* __restrict__ poff, int NB)
{
    int lane = threadIdx.x;                   // 64 threads
    if (NB <= 64) {
        int v = (lane < NB) ? psum[lane] : 0;
        int incl = v;
        #pragma unroll
        for (int off = 1; off < 64; off <<= 1) {
            int u = __shfl_up(incl, off);
            if (lane >= off) incl += u;
        }
        if (lane < NB) poff[lane] = incl - v;
    } else if (lane == 0) {
        int run = 0;
        for (int b = 0; b < NB; ++b) { poff[b] = run; run += psum[b]; }
    }
}

__global__ __launch_bounds__(256) void k_emit(
    const int* __restrict__ deg, const int* __restrict__ poff,
    int* __restrict__ rowptr, int* __restrict__ adj, int N)
{
    __shared__ int wsum[4];
    const int t = threadIdx.x, lane = t & 63, w = t >> 6;
    const int i0 = blockIdx.x * 1024 + t * 4;
    int d[4];
    #pragma unroll
    for (int q = 0; q < 4; ++q) d[q] = (i0 + q < N) ? deg[i0 + q] : 0;
    int ts = d[0] + d[1] + d[2] + d[3];
    int incl = ts;
    #pragma unroll
    for (int off = 1; off < 64; off <<= 1) {
        int u = __shfl_up(incl, off);
        if (lane >= off) incl += u;
    }
    if (lane == 63) wsum[w] = incl;
    __syncthreads();
    int base = poff[blockIdx.x];
    for (int q = 0; q < w; ++q) base += wsum[q];
    int excl = base + (incl - ts);
    #pragma unroll
    for (int q = 0; q < 4; ++q) {
        int i = i0 + q;
        if (i < N) {
            rowptr[i] = excl;
            adj[excl] = i;                    // self-loop first
            excl += d[q];
        }
    }
}

// ---- two-level radix partition of edges by dst bucket ----
// pass A: per-chunk LDS histogram; ONE global atomic per (block,bucket)
// reserves a contiguous range (low contention: <=NBLK-deep chains).
__global__ __launch_bounds__(256) void k_hist(
    const int* __restrict__ g, int E, int* __restrict__ bcnt,
    int* __restrict__ blockbase, int NBK)
{
    __shared__ int hist[256];
    const int t = threadIdx.x, blk = blockIdx.x;
    if (t < NBK) hist[t] = 0;
    __syncthreads();
    const int base = blk * CHUNK;
    const int end = min(base + CHUNK, E);
    for (int e = base + t; e < end; e += 256)
        atomicAdd(&hist[g[E + e] >> BKB2], 1);
    __syncthreads();
    if (t < NBK) {
        int c = hist[t];
        blockbase[blk * NBK + t] = c ? atomicAdd(&bcnt[t], c) : 0;
    }
}

__global__ void k_bucket_scan(const int* __restrict__ bcnt,
                              int* __restrict__ boff, int NBK)
{
    __shared__ int s[512];
    const int t = threadIdx.x;                // 256 threads
    if (t < NBK) s[t] = bcnt[t];
    __syncthreads();
    if (t == 0) {
        int run = 0;
        for (int b = 0; b < NBK; ++b) { int v = s[b]; s[b] = run; run += v; }
        boff[NBK] = run;
    }
    __syncthreads();
    if (t < NBK) boff[t] = s[t];
}

// pass B: re-read edges; LDS cursors allocate within reserved ranges; pairs
// writes land in ~CHUNK/NBK-long contiguous runs (full cache lines).
__global__ __launch_bounds__(256) void k_bin2(
    const int* __restrict__ g, int E, const int* __restrict__ boff,
    const int* __restrict__ blockbase, int2* __restrict__ pairs, int NBK)
{
    __shared__ int cur[256];
    const int t = threadIdx.x, blk = blockIdx.x;
    if (t < NBK) cur[t] = boff[t] + blockbase[blk * NBK + t];
    __syncthreads();
    const int base = blk * CHUNK;
    const int end = min(base + CHUNK, E);
    for (int e = base + t; e < end; e += 256) {
        int s = g[e], d = g[E + e];
        int pos = atomicAdd(&cur[d >> BKB2], 1);
        pairs[pos] = make_int2(s, d);
    }
}

// pass C: one block per 256-node bucket; LDS cursors; adj writes land in a
// ~17 KB window (L2-resident).
__global__ __launch_bounds__(256) void k_scatter2(
    const int2* __restrict__ pairs, const int* __restrict__ boff,
    const int* __restrict__ rowptr, int* __restrict__ adj, int N)
{
    __shared__ int cur[256];
    const int b = blockIdx.x, t = threadIdx.x;
    const int node = b * 256 + t;
    cur[t] = (node < N) ? rowptr[node] + 1 : 0;   // after self-loop
    __syncthreads();
    const int lo = boff[b], hi = boff[b + 1];
    for (int i = lo + t; i < hi; i += 256) {
        int2 p = pairs[i];
        int pos = atomicAdd(&cur[p.y & 255], 1);
        adj[pos] = p.x;
    }
}

// ==================== setup: alpha-weight folding + MLP collapse ============
__global__ void k_setup(
    const float* __restrict__ W1, const float* __restrict__ as1,
    const float* __restrict__ ad1,
    const float* __restrict__ W2, const float* __restrict__ as2,
    const float* __restrict__ ad2,
    const float* __restrict__ lw1, const float* __restrict__ lb1,
    const float* __restrict__ lw2, const float* __restrict__ lb2,
    float* __restrict__ wsd1, float* __restrict__ wsd2,
    float* __restrict__ weff)
{
    int t = threadIdx.x;                      // 832 threads
    if (t < 768) {
        int layer = (t >= 384);
        int r = t - layer * 384;              // r in [0,384)
        int k = r / 12, j = r - k * 12;
        const float* W = layer ? W2 : W1;
        const float* a = (j < 6) ? (layer ? as2 : as1) : (layer ? ad2 : ad1);
        int h = (j < 6) ? j : j - 6;
        float acc = 0.f;
        #pragma unroll
        for (int c = 0; c < 32; ++c)
            acc = fmaf(W[k * 192 + h * 32 + c], a[h * 32 + c], acc);
        (layer ? wsd2 : wsd1)[k * 12 + j] = acc;
    } else {
        int i = t - 768;                      // 0..63
        float acc = 0.f;
        for (int o = 0; o < 64; ++o) acc += lw1[i * 64 + o] * lw2[o];
        weff[i] = acc;
        if (i == 0) {
            float b = lb2[0];
            for (int o = 0; o < 64; ++o) b += lb1[o] * lw2[o];
            weff[64] = b;
        }
    }
}

// ==================== node prep =============================================
// One block per TILE nodes. Thread t owns output column t = h*32+c.
// xhp layout: [n][c][h] halves -> 12 B per (n,c), row = 384 B.
// asrcp/adstp: [n][h] fp16, row stride HP8 halves (16 B).
__global__ __launch_bounds__(192) void k_node_prep(
    const float* __restrict__ xsrc, const int* __restrict__ gidx,
    const float* __restrict__ W, const float* __restrict__ wsd,
    __half* __restrict__ xhp, __half* __restrict__ asrcp,
    __half* __restrict__ adstp, int N)
{
    __shared__ float xs[TILE * 33];           // stride 33: bank-conflict-free
    __shared__ int   rows[TILE];
    __shared__ float wsd_s[32 * 12];
    const int t = threadIdx.x;

    float wcol[32];
    #pragma unroll
    for (int k = 0; k < 32; ++k) wcol[k] = W[k * 192 + t];
    for (int i = t; i < 32 * 12; i += 192) wsd_s[i] = wsd[i];

    const int h = t >> 5;
    const int c = t & 31;
    const int n0 = blockIdx.x * TILE;
    if (t < TILE) {
        int n = n0 + t;
        rows[t] = (n < N) ? (gidx ? gidx[n] : n) : -1;
    }
    __syncthreads();
    if (t < TILE * 8) {                       // 16 rows x 8 float4
        int m = t >> 3, q = t & 7;
        int r = rows[m];
        float4 v = (r >= 0) ? *(const float4*)(xsrc + (size_t)r * 32 + q * 4)
                            : make_float4(0.f, 0.f, 0.f, 0.f);
        float* dst = xs + m * 33 + q * 4;
        dst[0] = v.x; dst[1] = v.y; dst[2] = v.z; dst[3] = v.w;
    }
    __syncthreads();

    const int nvalid = min(TILE, N - n0);
    const int xoff = c * 6 + h;               // channel-major packed half index
    #pragma unroll 4
    for (int m = 0; m < TILE; ++m) {
        const float* xr = xs + m * 33;
        float a = 0.f;
        #pragma unroll
        for (int k = 0; k < 32; ++k) a = fmaf(xr[k], wcol[k], a);
        if (m < nvalid)
            xhp[(size_t)(n0 + m) * 192 + xoff] = __float2half(a);
    }

    // alpha: thread t -> (node m = t/12, j = t%12); 16*12 = 192 = blockDim.
    {
        int m = t / 12, j = t - m * 12;
        if (m < nvalid) {
            const float* xr = xs + m * 33;
            float a = 0.f;
            #pragma unroll
            for (int k = 0; k < 32; ++k) a = fmaf(xr[k], wsd_s[k * 12 + j], a);
            if (j < 6) asrcp[(size_t)(n0 + m) * HP8 + j] = __float2half(a);
            else       adstp[(size_t)(n0 + m) * HP8 + (j - 6)] = __float2half(a);
        }
    }
}

// ==================== fused softmax + aggregation ===========================
// One 64-lane wave per node. lane = channel c in both halves; the two halves
// process EVEN/ODD edges respectively (accumulators merged at the end).
// Per 32-edge chunk: lane el computes edge el's 6 exp-weights, packs a 16 B
// record (s_byteoff, w01, w23, w45 as half2) into LDS; gather loop reads the
// record with one broadcast ds_read_b128, ONE dwordx3 load (6 halves at
// [n][c][h]) and 3 hfma2.  No max-subtraction (scores are O(0.1)).
template<int FUSE>
__global__ __launch_bounds__(256) void k_gat_node(
    const int* __restrict__ rowptr, const int* __restrict__ deg,
    const int* __restrict__ adj,
    const __half* __restrict__ asrcp, const __half* __restrict__ adstp,
    const __half* __restrict__ xhp, const float* __restrict__ bias,
    float* __restrict__ y, int N,
    const int* __restrict__ user, const float* __restrict__ u_table,
    const float* __restrict__ weff, float* __restrict__ out)
{
    __shared__ float4 st[4][32];
    const int wv = threadIdx.x >> 6;
    const int n = blockIdx.x * 4 + wv;
    if (n >= N) return;
    const int lane = threadIdx.x & 63;
    const int half = lane >> 5;
    const int c = lane & 31;
    const int el = lane & 31;

    // dst alphas (uniform per node)
    const __half2 adA = *(const __half2*)(adstp + (size_t)n * HP8 + 0);
    const __half2 adB = *(const __half2*)(adstp + (size_t)n * HP8 + 2);
    const __half2 adC = *(const __half2*)(adstp + (size_t)n * HP8 + 4);
    const float ad0 = __low2float(adA), ad1 = __high2float(adA);
    const float ad2 = __low2float(adB), ad3 = __high2float(adB);
    const float ad4 = __low2float(adC), ad5 = __high2float(adC);

    const int start = rowptr[n];
    const int dg = deg[n];
    const char* xcb = (const char*)xhp + c * 12;   // channel base

    __half2 acc0 = __float2half2_rn(0.f);
    __half2 acc1 = __float2half2_rn(0.f);
    __half2 acc2 = __float2half2_rn(0.f);
    float dl0 = 0.f, dl1 = 0.f, dl2 = 0.f, dl3 = 0.f, dl4 = 0.f, dl5 = 0.f;

    for (int base = 0; base < dg; base += 32) {
        const int rem = dg - base;
        const bool valid = el < rem;
        const int s = valid ? adj[start + base + el] : 0;
        // src alphas: one float4 = 8 halves (6 used)
        const float4 av = *(const float4*)(asrcp + (size_t)s * HP8);
        const __half2 aA = *(const __half2*)&av.x;
        const __half2 aB = *(const __half2*)&av.y;
        const __half2 aC = *(const __half2*)&av.z;
        float v0 = __low2float(aA) + ad0, v1 = __high2float(aA) + ad1;
        float v2 = __low2float(aB) + ad2, v3 = __high2float(aB) + ad3;
        float v4 = __low2float(aC) + ad4, v5 = __high2float(aC) + ad5;
        v0 = fmaxf(v0, NEG_SLOPE * v0); v1 = fmaxf(v1, NEG_SLOPE * v1);
        v2 = fmaxf(v2, NEG_SLOPE * v2); v3 = fmaxf(v3, NEG_SLOPE * v3);
        v4 = fmaxf(v4, NEG_SLOPE * v4); v5 = fmaxf(v5, NEG_SLOPE * v5);
        const float w0 = valid ? __expf(v0) : 0.f;
        const float w1 = valid ? __expf(v1) : 0.f;
        const float w2 = valid ? __expf(v2) : 0.f;
        const float w3 = valid ? __expf(v3) : 0.f;
        const float w4 = valid ? __expf(v4) : 0.f;
        const float w5 = valid ? __expf(v5) : 0.f;
        dl0 += w0; dl1 += w1; dl2 += w2; dl3 += w3; dl4 += w4; dl5 += w5;
        float4 rec;
        rec.x = __int_as_float(s * 384);
        const __half2 w01 = __floats2half2_rn(w0, w1);
        const __half2 w23 = __floats2half2_rn(w2, w3);
        const __half2 w45 = __floats2half2_rn(w4, w5);
        rec.y = *(const float*)&w01;
        rec.z = *(const float*)&w23;
        rec.w = *(const float*)&w45;
        if (lane < 32) st[wv][el] = rec;      // half 0 writes records

        // gather: halves take even/odd edges; pad records are zero-weight
        const int cnt = min(32, rem);
        int npairs = (cnt + 1) >> 1;
        npairs = (npairs + 1) & ~1;           // even trip, slots < 32 all valid
        for (int i = 0; i < npairs; i += 2) {
            #pragma unroll
            for (int q = 0; q < 2; ++q) {
                const float4 r = st[wv][2 * (i + q) + half];
                const char* p = xcb + __float_as_int(r.x);
                const uint3 dv = *(const uint3*)p;        // 6 halves (12 B)
                acc0 = __hfma2(*(const __half2*)&r.y, *(const __half2*)&dv.x, acc0);
                acc1 = __hfma2(*(const __half2*)&r.z, *(const __half2*)&dv.y, acc1);
                acc2 = __hfma2(*(const __half2*)&r.w, *(const __half2*)&dv.z, acc2);
            }
        }
    }

    // combine halves (even/odd edge partial sums)
    float s0 = __low2float(acc0), s1 = __high2float(acc0);
    float s2 = __low2float(acc1), s3 = __high2float(acc1);
    float s4 = __low2float(acc2), s5 = __high2float(acc2);
    s0 += __shfl_xor(s0, 32); s1 += __shfl_xor(s1, 32);
    s2 += __shfl_xor(s2, 32); s3 += __shfl_xor(s3, 32);
    s4 += __shfl_xor(s4, 32); s5 += __shfl_xor(s5, 32);
    // reduce denominators over the 32 edge-slots (halves identical)
    #pragma unroll
    for (int o = 1; o <= 16; o <<= 1) {
        dl0 += __shfl_xor(dl0, o); dl1 += __shfl_xor(dl1, o);
        dl2 += __shfl_xor(dl2, o); dl3 += __shfl_xor(dl3, o);
        dl4 += __shfl_xor(dl4, o); dl5 += __shfl_xor(dl5, o);
    }
    const float r = s0 / (dl0 + 1e-16f) + s1 / (dl1 + 1e-16f)
                  + s2 / (dl2 + 1e-16f) + s3 / (dl3 + 1e-16f)
                  + s4 / (dl4 + 1e-16f) + s5 / (dl5 + 1e-16f);
    const float yv = r * (1.f / 6.f) + bias[c];

    if (FUSE == 0) {
        if (half == 0) y[(size_t)n * 32 + c] = yv;
    } else {
        // out[n] = sigmoid([u_emb | y].weff + b): half0 lanes dot the y part,
        // half1 lanes dot the u part, then full-wave reduce.
        float p = (half == 0) ? yv * weff[32 + c]
                              : u_table[(size_t)user[n] * 32 + c] * weff[c];
        #pragma unroll
        for (int o = 32; o > 0; o >>= 1) p += __shfl_xor(p, o);
        if (lane == 0) out[n] = 1.f / (1.f + __expf(-(p + weff[64])));
    }
}

// ==================== launch ================================================

extern "C" void kernel_launch(void* const* d_in, const int* in_sizes, int n_in,
                              void* d_out, int out_size, void* d_ws, size_t ws_size,
                              hipStream_t stream)
{
    const int*   user    = (const int*)  d_in[0];
    const int*   item    = (const int*)  d_in[1];
    const int*   graph   = (const int*)  d_in[2];
    const float* u_table = (const float*)d_in[3];
    const float* i_table = (const float*)d_in[4];
    const float* W1      = (const float*)d_in[5];
    const float* a_src1  = (const float*)d_in[6];
    const float* a_dst1  = (const float*)d_in[7];
    const float* b1      = (const float*)d_in[8];
    const float* W2      = (const float*)d_in[9];
    const float* a_src2  = (const float*)d_in[10];
    const float* a_dst2  = (const float*)d_in[11];
    const float* b2      = (const float*)d_in[12];
    const float* lw1     = (const float*)d_in[13];
    const float* lb1     = (const float*)d_in[14];
    const float* lw2     = (const float*)d_in[15];
    const float* lb2     = (const float*)d_in[16];

    const int B  = in_sizes[0];
    const int N  = B;
    const int E  = in_sizes[2] / 2;
    const int Et = E + N;
    const int NB = (N + 1023) / 1024;
    const int NBK = (N + 255) / 256;          // 256-node buckets (<=256)
    const int NBLK = (E + CHUNK - 1) / CHUNK;

    float* ws = (float*)d_ws;
    size_t off = 0;
    __half* xhp   = (__half*)(ws + off); off += (size_t)N * 96;  // N*192 halves
    __half* asrcp = (__half*)(ws + off); off += (size_t)N * 4;   // N*8 halves
    __half* adstp = (__half*)(ws + off); off += (size_t)N * 4;
    float* y1     = ws + off; off += (size_t)N * 32;
    float* weff   = ws + off; off += 128;
    float* wsd1   = ws + off; off += 384;
    float* wsd2   = ws + off; off += 384;
    int*   deg    = (int*)(ws + off); off += N;
    int*   rowptr = (int*)(ws + off); off += N;
    int*   psum   = (int*)(ws + off); off += NB + 1;
    int*   poff   = (int*)(ws + off); off += NB + 1;
    int*   bcnt   = (int*)(ws + off); off += NBK + 1;
    int*   boff   = (int*)(ws + off); off += NBK + 1;
    int*   bbase  = (int*)(ws + off); off += (size_t)NBLK * NBK;
    int*   adj    = (int*)(ws + off); off += Et + 2;
    off = (off + 1) & ~(size_t)1;             // align int2
    int2*  pairs  = (int2*)(ws + off); off += (size_t)E * 2;

    const int egrid = (E + 255) / 256;
    const int ngrid = (N + 255) / 256;
    const int ggrid = (N + 3) / 4;
    const int pgrid = (N + TILE - 1) / TILE;

    // ---- CSR build (once; graph shared by both layers) ----
    hipLaunchKernelGGL(k_init_deg, dim3(ngrid), dim3(256), 0, stream,
        deg, N, bcnt, NBK);
    hipLaunchKernelGGL(k_count,    dim3(egrid), dim3(256), 0, stream, graph, E, deg);
    hipLaunchKernelGGL(k_block_sum, dim3(NB), dim3(256), 0, stream, deg, psum, N);
    hipLaunchKernelGGL(k_scan_partials, dim3(1), dim3(64), 0, stream, psum, poff, NB);
    hipLaunchKernelGGL(k_emit, dim3(NB), dim3(256), 0, stream,
        deg, poff, rowptr, adj, N);
    // two-level radix partition of edges by dst bucket
    hipLaunchKernelGGL(k_hist, dim3(NBLK), dim3(256), 0, stream,
        graph, E, bcnt, bbase, NBK);
    hipLaunchKernelGGL(k_bucket_scan, dim3(1), dim3(256), 0, stream,
        bcnt, boff, NBK);
    hipLaunchKernelGGL(k_bin2, dim3(NBLK), dim3(256), 0, stream,
        graph, E, boff, bbase, pairs, NBK);
    hipLaunchKernelGGL(k_scatter2, dim3(NBK), dim3(256), 0, stream,
        pairs, boff, rowptr, adj, N);

    // ---- setup: fold alpha vectors into W (both layers) + MLP collapse ----
    hipLaunchKernelGGL(k_setup, dim3(1), dim3(832), 0, stream,
        W1, a_src1, a_dst1, W2, a_src2, a_dst2,
        lw1, lb1, lw2, lb2, wsd1, wsd2, weff);

    // ---- GAT layer 1 (input: i_table gathered by item) ----
    hipLaunchKernelGGL(k_node_prep, dim3(pgrid), dim3(192), 0, stream,
        i_table, item, W1, wsd1, xhp, asrcp, adstp, N);
    hipLaunchKernelGGL(k_gat_node<0>, dim3(ggrid), dim3(256), 0, stream,
        rowptr, deg, adj, asrcp, adstp, xhp, b1, y1, N,
        (const int*)nullptr, (const float*)nullptr,
        (const float*)nullptr, (float*)nullptr);

    // ---- GAT layer 2 (input: y1) + fused MLP head + sigmoid ----
    hipLaunchKernelGGL(k_node_prep, dim3(pgrid), dim3(192), 0, stream,
        y1, (const int*)nullptr, W2, wsd2, xhp, asrcp, adstp, N);
    hipLaunchKernelGGL(k_gat_node<1>, dim3(ggrid), dim3(256), 0, stream,
        rowptr, deg, adj, asrcp, adstp, xhp, b2, (float*)nullptr, N,
        user, u_table, weff, (float*)d_out);
}

// Round 10
// 240.325 us; speedup vs baseline: 2.1672x; 1.1641x over previous
//
#include <hip/hip_runtime.h>
#include <hip/hip_fp16.h>
#include <math.h>

#define HP8 8     // halves per packed alpha row (6 heads + 2 pad)
#define NEG_SLOPE 0.2f
#define TILE 16   // nodes per k_node_prep block
#define BKB2 8    // bucket = dst >> 8  (256 nodes per bucket)
#define CHUNK 16384

// ==================== edge partition (graph identical for both layers) =====
// pass A: per-chunk LDS histogram over dst buckets; ONE global atomic per
// (block,bucket) reserves a contiguous range (<=NBLK-deep chains).
__global__ __launch_bounds__(256) void k_hist(
    const int* __restrict__ g, int E, int* __restrict__ bcnt,
    int* __restrict__ blockbase, int NBK)
{
    __shared__ int hist[256];
    const int t = threadIdx.x, blk = blockIdx.x;
    hist[t] = 0;
    __syncthreads();
    const int base = blk * CHUNK;
    const int end = min(base + CHUNK, E);
    for (int e = base + t; e < end; e += 256)
        atomicAdd(&hist[g[E + e] >> BKB2], 1);
    __syncthreads();
    if (t < NBK) {
        int c = hist[t];
        blockbase[blk * NBK + t] = c ? atomicAdd(&bcnt[t], c) : 0;
    }
}

__global__ void k_bucket_scan(const int* __restrict__ bcnt,
                              int* __restrict__ boff, int NBK)
{
    __shared__ int s[512];
    const int t = threadIdx.x;                // 256 threads
    if (t < NBK) s[t] = bcnt[t];
    __syncthreads();
    if (t == 0) {
        int run = 0;
        for (int b = 0; b < NBK; ++b) { int v = s[b]; s[b] = run; run += v; }
        boff[NBK] = run;
    }
    __syncthreads();
    if (t < NBK) boff[t] = s[t];
}

// pass B: re-read edges; LDS cursors allocate within reserved ranges; pairs
// writes land in contiguous runs (full cache lines).
__global__ __launch_bounds__(256) void k_bin2(
    const int* __restrict__ g, int E, const int* __restrict__ boff,
    const int* __restrict__ blockbase, int2* __restrict__ pairs, int NBK)
{
    __shared__ int cur[256];
    const int t = threadIdx.x, blk = blockIdx.x;
    if (t < NBK) cur[t] = boff[t] + blockbase[blk * NBK + t];
    __syncthreads();
    const int base = blk * CHUNK;
    const int end = min(base + CHUNK, E);
    for (int e = base + t; e < end; e += 256) {
        int s = g[e], d = g[E + e];
        int pos = atomicAdd(&cur[d >> BKB2], 1);
        pairs[pos] = make_int2(s, d);
    }
}

// pass C: one block per 256-node bucket. Derive per-node counts from the
// bucket's pairs (LDS), in-block scan -> rowptr/deg, write self-loop, then
// scatter adj via LDS cursors (writes land in a ~17 KB L2-resident window).
__global__ __launch_bounds__(256) void k_build(
    const int2* __restrict__ pairs, const int* __restrict__ boff,
    int* __restrict__ rowptr, int* __restrict__ deg, int* __restrict__ adj,
    int N)
{
    __shared__ int cnt[256];
    __shared__ int cur[256];
    __shared__ int wsum[4];
    const int b = blockIdx.x, t = threadIdx.x, lane = t & 63, w = t >> 6;
    cnt[t] = 0;
    __syncthreads();
    const int lo = boff[b], hi = boff[b + 1];
    for (int i = lo + t; i < hi; i += 256)
        atomicAdd(&cnt[pairs[i].y & 255], 1);
    __syncthreads();
    const int v = cnt[t];
    int incl = v;
    #pragma unroll
    for (int off = 1; off < 64; off <<= 1) {
        int u = __shfl_up(incl, off);
        if (lane >= off) incl += u;
    }
    if (lane == 63) wsum[w] = incl;
    __syncthreads();
    int base = 0;
    for (int q = 0; q < w; ++q) base += wsum[q];
    const int excl = base + incl - v;
    const int node = b * 256 + t;
    const int abase = lo + b * 256;           // adj slots before this bucket
    if (node < N) {
        const int rp = abase + excl + t;      // + t self-loop slots in-bucket
        rowptr[node] = rp;
        deg[node] = v + 1;
        adj[rp] = node;                       // self-loop first
        cur[t] = rp + 1;
    } else cur[t] = 0;
    __syncthreads();
    for (int i = lo + t; i < hi; i += 256) {
        int2 p = pairs[i];
        int pos = atomicAdd(&cur[p.y & 255], 1);
        adj[pos] = p.x;
    }
}

// ==================== setup: alpha-weight folding + MLP collapse ============
__global__ void k_setup(
    const float* __restrict__ W1, const float* __restrict__ as1,
    const float* __restrict__ ad1,
    const float* __restrict__ W2, const float* __restrict__ as2,
    const float* __restrict__ ad2,
    const float* __restrict__ lw1, const float* __restrict__ lb1,
    const float* __restrict__ lw2, const float* __restrict__ lb2,
    float* __restrict__ wsd1, float* __restrict__ wsd2,
    float* __restrict__ weff)
{
    int t = threadIdx.x;                      // 832 threads
    if (t < 768) {
        int layer = (t >= 384);
        int r = t - layer * 384;              // r in [0,384)
        int k = r / 12, j = r - k * 12;
        const float* W = layer ? W2 : W1;
        const float* a = (j < 6) ? (layer ? as2 : as1) : (layer ? ad2 : ad1);
        int h = (j < 6) ? j : j - 6;
        float acc = 0.f;
        #pragma unroll
        for (int c = 0; c < 32; ++c)
            acc = fmaf(W[k * 192 + h * 32 + c], a[h * 32 + c], acc);
        (layer ? wsd2 : wsd1)[k * 12 + j] = acc;
    } else {
        int i = t - 768;                      // 0..63
        float acc = 0.f;
        for (int o = 0; o < 64; ++o) acc += lw1[i * 64 + o] * lw2[o];
        weff[i] = acc;
        if (i == 0) {
            float b = lb2[0];
            for (int o = 0; o < 64; ++o) b += lb1[o] * lw2[o];
            weff[64] = b;
        }
    }
}

// ==================== node prep =============================================
// One block per TILE nodes. Thread t owns output column t = h*32+c.
// xhp layout: [n][c][h] halves -> 12 B per (n,c), row = 384 B.
// asrcp/adstp: [n][h] fp16, row stride HP8 halves (16 B).
__global__ __launch_bounds__(192) void k_node_prep(
    const float* __restrict__ xsrc, const int* __restrict__ gidx,
    const float* __restrict__ W, const float* __restrict__ wsd,
    __half* __restrict__ xhp, __half* __restrict__ asrcp,
    __half* __restrict__ adstp, int N)
{
    __shared__ float xs[TILE * 33];           // stride 33: bank-conflict-free
    __shared__ int   rows[TILE];
    __shared__ float wsd_s[32 * 12];
    const int t = threadIdx.x;

    float wcol[32];
    #pragma unroll
    for (int k = 0; k < 32; ++k) wcol[k] = W[k * 192 + t];
    for (int i = t; i < 32 * 12; i += 192) wsd_s[i] = wsd[i];

    const int h = t >> 5;
    const int c = t & 31;
    const int n0 = blockIdx.x * TILE;
    if (t < TILE) {
        int n = n0 + t;
        rows[t] = (n < N) ? (gidx ? gidx[n] : n) : -1;
    }
    __syncthreads();
    if (t < TILE * 8) {                       // 16 rows x 8 float4
        int m = t >> 3, q = t & 7;
        int r = rows[m];
        float4 v = (r >= 0) ? *(const float4*)(xsrc + (size_t)r * 32 + q * 4)
                            : make_float4(0.f, 0.f, 0.f, 0.f);
        float* dst = xs + m * 33 + q * 4;
        dst[0] = v.x; dst[1] = v.y; dst[2] = v.z; dst[3] = v.w;
    }
    __syncthreads();

    const int nvalid = min(TILE, N - n0);
    const int xoff = c * 6 + h;               // channel-major packed half index
    #pragma unroll 4
    for (int m = 0; m < TILE; ++m) {
        const float* xr = xs + m * 33;
        float a = 0.f;
        #pragma unroll
        for (int k = 0; k < 32; ++k) a = fmaf(xr[k], wcol[k], a);
        if (m < nvalid)
            xhp[(size_t)(n0 + m) * 192 + xoff] = __float2half(a);
    }

    // alpha: thread t -> (node m = t/12, j = t%12); 16*12 = 192 = blockDim.
    {
        int m = t / 12, j = t - m * 12;
        if (m < nvalid) {
            const float* xr = xs + m * 33;
            float a = 0.f;
            #pragma unroll
            for (int k = 0; k < 32; ++k) a = fmaf(xr[k], wsd_s[k * 12 + j], a);
            if (j < 6) asrcp[(size_t)(n0 + m) * HP8 + j] = __float2half(a);
            else       adstp[(size_t)(n0 + m) * HP8 + (j - 6)] = __float2half(a);
        }
    }
}

// ==================== fused softmax + aggregation ===========================
// One 64-lane wave per node. lane = channel c in both halves; the two halves
// process EVEN/ODD edges respectively (accumulators merged at the end).
// Per 32-edge chunk: lane el computes edge el's 6 exp-weights, packs a 16 B
// record (s_byteoff, w01, w23, w45 as half2) into LDS; gather loop reads the
// record with a broadcast ds_read_b128 and ONE dwordx3 (6 halves, [n][c][h])
// + 3 hfma2.  Gather trip is padded to a multiple of 4 -> 4 loads in flight
// (pad records are zero-weight).  No max-subtraction (scores are O(0.1)).
template<int FUSE>
__global__ __launch_bounds__(256) void k_gat_node(
    const int* __restrict__ rowptr, const int* __restrict__ deg,
    const int* __restrict__ adj,
    const __half* __restrict__ asrcp, const __half* __restrict__ adstp,
    const __half* __restrict__ xhp, const float* __restrict__ bias,
    float* __restrict__ y, int N,
    const int* __restrict__ user, const float* __restrict__ u_table,
    const float* __restrict__ weff, float* __restrict__ out)
{
    __shared__ float4 st[4][32];
    const int wv = threadIdx.x >> 6;
    const int n = blockIdx.x * 4 + wv;
    if (n >= N) return;
    const int lane = threadIdx.x & 63;
    const int half = lane >> 5;
    const int c = lane & 31;
    const int el = lane & 31;

    // dst alphas (uniform per node)
    const __half2 adA = *(const __half2*)(adstp + (size_t)n * HP8 + 0);
    const __half2 adB = *(const __half2*)(adstp + (size_t)n * HP8 + 2);
    const __half2 adC = *(const __half2*)(adstp + (size_t)n * HP8 + 4);
    const float ad0 = __low2float(adA), ad1 = __high2float(adA);
    const float ad2 = __low2float(adB), ad3 = __high2float(adB);
    const float ad4 = __low2float(adC), ad5 = __high2float(adC);

    const int start = rowptr[n];
    const int dg = deg[n];
    const char* xcb = (const char*)xhp + c * 12;   // channel base

    __half2 acc0 = __float2half2_rn(0.f);
    __half2 acc1 = __float2half2_rn(0.f);
    __half2 acc2 = __float2half2_rn(0.f);
    float dl0 = 0.f, dl1 = 0.f, dl2 = 0.f, dl3 = 0.f, dl4 = 0.f, dl5 = 0.f;

    for (int base = 0; base < dg; base += 32) {
        const int rem = dg - base;
        const bool valid = el < rem;
        const int s = valid ? adj[start + base + el] : 0;
        // src alphas: one float4 = 8 halves (6 used)
        const float4 av = *(const float4*)(asrcp + (size_t)s * HP8);
        const __half2 aA = *(const __half2*)&av.x;
        const __half2 aB = *(const __half2*)&av.y;
        const __half2 aC = *(const __half2*)&av.z;
        float v0 = __low2float(aA) + ad0, v1 = __high2float(aA) + ad1;
        float v2 = __low2float(aB) + ad2, v3 = __high2float(aB) + ad3;
        float v4 = __low2float(aC) + ad4, v5 = __high2float(aC) + ad5;
        v0 = fmaxf(v0, NEG_SLOPE * v0); v1 = fmaxf(v1, NEG_SLOPE * v1);
        v2 = fmaxf(v2, NEG_SLOPE * v2); v3 = fmaxf(v3, NEG_SLOPE * v3);
        v4 = fmaxf(v4, NEG_SLOPE * v4); v5 = fmaxf(v5, NEG_SLOPE * v5);
        const float w0 = valid ? __expf(v0) : 0.f;
        const float w1 = valid ? __expf(v1) : 0.f;
        const float w2 = valid ? __expf(v2) : 0.f;
        const float w3 = valid ? __expf(v3) : 0.f;
        const float w4 = valid ? __expf(v4) : 0.f;
        const float w5 = valid ? __expf(v5) : 0.f;
        dl0 += w0; dl1 += w1; dl2 += w2; dl3 += w3; dl4 += w4; dl5 += w5;
        float4 rec;
        rec.x = __int_as_float(s * 384);
        const __half2 w01 = __floats2half2_rn(w0, w1);
        const __half2 w23 = __floats2half2_rn(w2, w3);
        const __half2 w45 = __floats2half2_rn(w4, w5);
        rec.y = *(const float*)&w01;
        rec.z = *(const float*)&w23;
        rec.w = *(const float*)&w45;
        if (lane < 32) st[wv][el] = rec;      // half 0 writes records

        // gather: halves take even/odd edges; trip padded to x4 so 4 loads
        // are in flight; pad records (slots < 32) are zero-weight.
        const int cnt = min(32, rem);
        const int nh = (((cnt + 1) >> 1) + 3) & ~3;   // per-half trip, x4
        for (int i = 0; i < nh; i += 4) {
            #pragma unroll
            for (int q = 0; q < 4; ++q) {
                const float4 r = st[wv][2 * (i + q) + half];
                const char* p = xcb + __float_as_int(r.x);
                const uint3 dv = *(const uint3*)p;        // 6 halves (12 B)
                acc0 = __hfma2(*(const __half2*)&r.y, *(const __half2*)&dv.x, acc0);
                acc1 = __hfma2(*(const __half2*)&r.z, *(const __half2*)&dv.y, acc1);
                acc2 = __hfma2(*(const __half2*)&r.w, *(const __half2*)&dv.z, acc2);
            }
        }
    }

    // combine halves (even/odd edge partial sums)
    float s0 = __low2float(acc0), s1 = __high2float(acc0);
    float s2 = __low2float(acc1), s3 = __high2float(acc1);
    float s4 = __low2float(acc2), s5 = __high2float(acc2);
    s0 += __shfl_xor(s0, 32); s1 += __shfl_xor(s1, 32);
    s2 += __shfl_xor(s2, 32); s3 += __shfl_xor(s3, 32);
    s4 += __shfl_xor(s4, 32); s5 += __shfl_xor(s5, 32);
    // reduce denominators over the 32 edge-slots (halves identical)
    #pragma unroll
    for (int o = 1; o <= 16; o <<= 1) {
        dl0 += __shfl_xor(dl0, o); dl1 += __shfl_xor(dl1, o);
        dl2 += __shfl_xor(dl2, o); dl3 += __shfl_xor(dl3, o);
        dl4 += __shfl_xor(dl4, o); dl5 += __shfl_xor(dl5, o);
    }
    const float r = s0 / (dl0 + 1e-16f) + s1 / (dl1 + 1e-16f)
                  + s2 / (dl2 + 1e-16f) + s3 / (dl3 + 1e-16f)
                  + s4 / (dl4 + 1e-16f) + s5 / (dl5 + 1e-16f);
    const float yv = r * (1.f / 6.f) + bias[c];

    if (FUSE == 0) {
        if (half == 0) y[(size_t)n * 32 + c] = yv;
    } else {
        // out[n] = sigmoid([u_emb | y].weff + b): half0 lanes dot the y part,
        // half1 lanes dot the u part, then full-wave reduce.
        float p = (half == 0) ? yv * weff[32 + c]
                              : u_table[(size_t)user[n] * 32 + c] * weff[c];
        #pragma unroll
        for (int o = 32; o > 0; o >>= 1) p += __shfl_xor(p, o);
        if (lane == 0) out[n] = 1.f / (1.f + __expf(-(p + weff[64])));
    }
}

// ==================== launch ================================================

extern "C" void kernel_launch(void* const* d_in, const int* in_sizes, int n_in,
                              void* d_out, int out_size, void* d_ws, size_t ws_size,
                              hipStream_t stream)
{
    const int*   user    = (const int*)  d_in[0];
    const int*   item    = (const int*)  d_in[1];
    const int*   graph   = (const int*)  d_in[2];
    const float* u_table = (const float*)d_in[3];
    const float* i_table = (const float*)d_in[4];
    const float* W1      = (const float*)d_in[5];
    const float* a_src1  = (const float*)d_in[6];
    const float* a_dst1  = (const float*)d_in[7];
    const float* b1      = (const float*)d_in[8];
    const float* W2      = (const float*)d_in[9];
    const float* a_src2  = (const float*)d_in[10];
    const float* a_dst2  = (const float*)d_in[11];
    const float* b2      = (const float*)d_in[12];
    const float* lw1     = (const float*)d_in[13];
    const float* lb1     = (const float*)d_in[14];
    const float* lw2     = (const float*)d_in[15];
    const float* lb2     = (const float*)d_in[16];

    const int B  = in_sizes[0];
    const int N  = B;
    const int E  = in_sizes[2] / 2;
    const int Et = E + N;
    const int NBK = (N + 255) / 256;          // 256-node buckets (<=256)
    const int NBLK = (E + CHUNK - 1) / CHUNK;

    float* ws = (float*)d_ws;
    size_t off = 0;
    __half* xhp   = (__half*)(ws + off); off += (size_t)N * 96;  // N*192 halves
    __half* asrcp = (__half*)(ws + off); off += (size_t)N * 4;   // N*8 halves
    __half* adstp = (__half*)(ws + off); off += (size_t)N * 4;
    float* y1     = ws + off; off += (size_t)N * 32;
    float* weff   = ws + off; off += 128;
    float* wsd1   = ws + off; off += 384;
    float* wsd2   = ws + off; off += 384;
    int*   deg    = (int*)(ws + off); off += N;
    int*   rowptr = (int*)(ws + off); off += N;
    int*   bcnt   = (int*)(ws + off); off += NBK + 1;
    int*   boff   = (int*)(ws + off); off += NBK + 1;
    int*   bbase  = (int*)(ws + off); off += (size_t)NBLK * NBK;
    int*   adj    = (int*)(ws + off); off += Et + 2;
    off = (off + 1) & ~(size_t)1;             // align int2
    int2*  pairs  = (int2*)(ws + off); off += (size_t)E * 2;

    const int ggrid = (N + 3) / 4;
    const int pgrid = (N + TILE - 1) / TILE;

    // ---- edge partition + CSR build (once; graph shared by both layers) ----
    hipMemsetAsync(bcnt, 0, (NBK + 1) * sizeof(int), stream);
    hipLaunchKernelGGL(k_hist, dim3(NBLK), dim3(256), 0, stream,
        graph, E, bcnt, bbase, NBK);
    hipLaunchKernelGGL(k_bucket_scan, dim3(1), dim3(256), 0, stream,
        bcnt, boff, NBK);
    hipLaunchKernelGGL(k_bin2, dim3(NBLK), dim3(256), 0, stream,
        graph, E, boff, bbase, pairs, NBK);
    hipLaunchKernelGGL(k_build, dim3(NBK), dim3(256), 0, stream,
        pairs, boff, rowptr, deg, adj, N);

    // ---- setup: fold alpha vectors into W (both layers) + MLP collapse ----
    hipLaunchKernelGGL(k_setup, dim3(1), dim3(832), 0, stream,
        W1, a_src1, a_dst1, W2, a_src2, a_dst2,
        lw1, lb1, lw2, lb2, wsd1, wsd2, weff);

    // ---- GAT layer 1 (input: i_table gathered by item) ----
    hipLaunchKernelGGL(k_node_prep, dim3(pgrid), dim3(192), 0, stream,
        i_table, item, W1, wsd1, xhp, asrcp, adstp, N);
    hipLaunchKernelGGL(k_gat_node<0>, dim3(ggrid), dim3(256), 0, stream,
        rowptr, deg, adj, asrcp, adstp, xhp, b1, y1, N,
        (const int*)nullptr, (const float*)nullptr,
        (const float*)nullptr, (float*)nullptr);

    // ---- GAT layer 2 (input: y1) + fused MLP head + sigmoid ----
    hipLaunchKernelGGL(k_node_prep, dim3(pgrid), dim3(192), 0, stream,
        y1, (const int*)nullptr, W2, wsd2, xhp, asrcp, adstp, N);
    hipLaunchKernelGGL(k_gat_node<1>, dim3(ggrid), dim3(256), 0, stream,
        rowptr, deg, adj, asrcp, adstp, xhp, b2, (float*)nullptr, N,
        user, u_table, weff, (float*)d_out);
}

// Round 11
// 214.092 us; speedup vs baseline: 2.4328x; 1.1225x over previous
//
#include <hip/hip_runtime.h>
#include <hip/hip_fp16.h>
#include <math.h>

#define NEG_SLOPE 0.2f
#define TILE 16   // nodes per k_prep / k_post block
#define BKB2 8    // bucket = dst >> 8  (256 nodes per bucket)
#define CHUNK 16384

// ==================== edge partition (graph identical for both layers) =====
__global__ __launch_bounds__(256) void k_hist(
    const int* __restrict__ g, int E, int* __restrict__ bcnt,
    int* __restrict__ blockbase, int NBK)
{
    __shared__ int hist[256];
    const int t = threadIdx.x, blk = blockIdx.x;
    hist[t] = 0;
    __syncthreads();
    const int base = blk * CHUNK;
    const int end = min(base + CHUNK, E);
    for (int e = base + t; e < end; e += 256)
        atomicAdd(&hist[g[E + e] >> BKB2], 1);
    __syncthreads();
    if (t < NBK) {
        int c = hist[t];
        blockbase[blk * NBK + t] = c ? atomicAdd(&bcnt[t], c) : 0;
    }
}

__global__ void k_bucket_scan(const int* __restrict__ bcnt,
                              int* __restrict__ boff, int NBK)
{
    __shared__ int s[512];
    const int t = threadIdx.x;                // 256 threads
    if (t < NBK) s[t] = bcnt[t];
    __syncthreads();
    if (t == 0) {
        int run = 0;
        for (int b = 0; b < NBK; ++b) { int v = s[b]; s[b] = run; run += v; }
        boff[NBK] = run;
    }
    __syncthreads();
    if (t < NBK) boff[t] = s[t];
}

__global__ __launch_bounds__(256) void k_bin2(
    const int* __restrict__ g, int E, const int* __restrict__ boff,
    const int* __restrict__ blockbase, int2* __restrict__ pairs, int NBK)
{
    __shared__ int cur[256];
    const int t = threadIdx.x, blk = blockIdx.x;
    if (t < NBK) cur[t] = boff[t] + blockbase[blk * NBK + t];
    __syncthreads();
    const int base = blk * CHUNK;
    const int end = min(base + CHUNK, E);
    for (int e = base + t; e < end; e += 256) {
        int s = g[e], d = g[E + e];
        int pos = atomicAdd(&cur[d >> BKB2], 1);
        pairs[pos] = make_int2(s, d);
    }
}

__global__ __launch_bounds__(256) void k_build(
    const int2* __restrict__ pairs, const int* __restrict__ boff,
    int* __restrict__ rowptr, int* __restrict__ deg, int* __restrict__ adj,
    int N)
{
    __shared__ int cnt[256];
    __shared__ int cur[256];
    __shared__ int wsum[4];
    const int b = blockIdx.x, t = threadIdx.x, lane = t & 63, w = t >> 6;
    cnt[t] = 0;
    __syncthreads();
    const int lo = boff[b], hi = boff[b + 1];
    for (int i = lo + t; i < hi; i += 256)
        atomicAdd(&cnt[pairs[i].y & 255], 1);
    __syncthreads();
    const int v = cnt[t];
    int incl = v;
    #pragma unroll
    for (int off = 1; off < 64; off <<= 1) {
        int u = __shfl_up(incl, off);
        if (lane >= off) incl += u;
    }
    if (lane == 63) wsum[w] = incl;
    __syncthreads();
    int base = 0;
    for (int q = 0; q < w; ++q) base += wsum[q];
    const int excl = base + incl - v;
    const int node = b * 256 + t;
    const int abase = lo + b * 256;
    if (node < N) {
        const int rp = abase + excl + t;
        rowptr[node] = rp;
        deg[node] = v + 1;
        adj[rp] = node;                       // self-loop first
        cur[t] = rp + 1;
    } else cur[t] = 0;
    __syncthreads();
    for (int i = lo + t; i < hi; i += 256) {
        int2 p = pairs[i];
        int pos = atomicAdd(&cur[p.y & 255], 1);
        adj[pos] = p.x;
    }
}

// ==================== setup: fold alphas into W, pack W as half2, MLP ======
// wsd[k][j]: j<6 -> (W a_src)[:,j], j>=6 -> (W a_dst)[:,j-6]  (f32).
// whalf[col][i] = half2(W[2i][col], W[2i+1][col]) for the post-multiply.
__global__ void k_setup(
    const float* __restrict__ W1, const float* __restrict__ as1,
    const float* __restrict__ ad1,
    const float* __restrict__ W2, const float* __restrict__ as2,
    const float* __restrict__ ad2,
    const float* __restrict__ lw1, const float* __restrict__ lb1,
    const float* __restrict__ lw2, const float* __restrict__ lb2,
    float* __restrict__ wsd1, float* __restrict__ wsd2,
    float* __restrict__ weff,
    unsigned int* __restrict__ whalf1, unsigned int* __restrict__ whalf2)
{
    int t = threadIdx.x;                      // 832 threads
    if (t < 768) {
        int layer = (t >= 384);
        int r = t - layer * 384;
        int k = r / 12, j = r - k * 12;
        const float* W = layer ? W2 : W1;
        const float* a = (j < 6) ? (layer ? as2 : as1) : (layer ? ad2 : ad1);
        int h = (j < 6) ? j : j - 6;
        float acc = 0.f;
        #pragma unroll
        for (int c = 0; c < 32; ++c)
            acc = fmaf(W[k * 192 + h * 32 + c], a[h * 32 + c], acc);
        (layer ? wsd2 : wsd1)[k * 12 + j] = acc;
    } else {
        int i = t - 768;                      // 0..63
        float acc = 0.f;
        for (int o = 0; o < 64; ++o) acc += lw1[i * 64 + o] * lw2[o];
        weff[i] = acc;
        if (i == 0) {
            float b = lb2[0];
            for (int o = 0; o < 64; ++o) b += lb1[o] * lw2[o];
            weff[64] = b;
        }
    }
    if (t < 384) {
        int layer = (t >= 192);
        int col = t - layer * 192;
        const float* W = layer ? W2 : W1;
        unsigned int* dst = layer ? whalf2 : whalf1;
        #pragma unroll
        for (int i = 0; i < 16; ++i) {
            __half2 p = __floats2half2_rn(W[(2 * i) * 192 + col],
                                          W[(2 * i + 1) * 192 + col]);
            dst[col * 16 + i] = *(unsigned int*)&p;
        }
    }
}

// ==================== prep: alphas (+ fp16 x cast for layer 1) ==============
// GATHER=1: read f32 rows via gidx, emit xp (fp16 rows) + asrc/adst (f32).
// GATHER=0: read fp16 rows directly (y1h), emit asrc/adst only.
template<int GATHER>
__global__ __launch_bounds__(192) void k_prep(
    const float* __restrict__ xf, const __half* __restrict__ xh,
    const int* __restrict__ gidx, const float* __restrict__ wsd,
    __half* __restrict__ xp,
    float* __restrict__ asrc, float* __restrict__ adst, int N)
{
    __shared__ float xs[TILE * 33];
    __shared__ int   rows[TILE];
    __shared__ float wsd_s[384];
    const int t = threadIdx.x;
    for (int i = t; i < 384; i += 192) wsd_s[i] = wsd[i];
    const int n0 = blockIdx.x * TILE;
    if (GATHER && t < TILE) {
        int n = n0 + t;
        rows[t] = (n < N) ? gidx[n] : -1;
    }
    __syncthreads();
    if (t < TILE * 8) {
        int m = t >> 3, q = t & 7;
        float* dst = xs + m * 33 + q * 4;
        if (GATHER) {
            int r = rows[m];
            float4 v = (r >= 0) ? *(const float4*)(xf + (size_t)r * 32 + q * 4)
                                : make_float4(0.f, 0.f, 0.f, 0.f);
            dst[0] = v.x; dst[1] = v.y; dst[2] = v.z; dst[3] = v.w;
            if (r >= 0) {
                __half2 p0 = __floats2half2_rn(v.x, v.y);
                __half2 p1 = __floats2half2_rn(v.z, v.w);
                uint2 u; u.x = *(unsigned int*)&p0; u.y = *(unsigned int*)&p1;
                *(uint2*)((unsigned int*)xp + (size_t)(n0 + m) * 16 + q * 2) = u;
            }
        } else {
            int n = n0 + m;
            uint2 u = (n < N)
                ? *(const uint2*)((const unsigned int*)xh + (size_t)n * 16 + q * 2)
                : make_uint2(0u, 0u);
            __half2 h0 = *(__half2*)&u.x, h1 = *(__half2*)&u.y;
            dst[0] = __low2float(h0); dst[1] = __high2float(h0);
            dst[2] = __low2float(h1); dst[3] = __high2float(h1);
        }
    }
    __syncthreads();
    const int m = t / 12, j = t - m * 12;     // 16*12 = 192
    const int n = n0 + m;
    if (n < N) {
        const float* xr = xs + m * 33;
        float a = 0.f;
        #pragma unroll
        for (int k = 0; k < 32; ++k) a = fmaf(xr[k], wsd_s[k * 12 + j], a);
        if (j < 6) asrc[(size_t)n * 8 + j] = a;
        else       adst[(size_t)n * 8 + (j - 6)] = a;
    }
}

// ==================== gather: z_h[c] = sum_e w_eh * x[src_e][c] =============
// One 64-lane wave per node; lane = channel c; halves take even/odd edges.
// Per edge: 64 B x-row (L2-resident, 3.2 MB total), f32 accumulation.
// No max-subtraction (scores are O(0.1); softmax is shift-invariant).
__global__ __launch_bounds__(256) void k_gat(
    const int* __restrict__ rowptr, const int* __restrict__ deg,
    const int* __restrict__ adj,
    const float* __restrict__ asrc, const float* __restrict__ adst,
    const __half* __restrict__ xp, __half* __restrict__ zn, int N)
{
    __shared__ float4 st0[4][32];
    __shared__ float4 st1[4][32];
    const int wv = threadIdx.x >> 6;
    const int n = blockIdx.x * 4 + wv;
    if (n >= N) return;
    const int lane = threadIdx.x & 63;
    const int half = lane >> 5;
    const int c = lane & 31;
    const int el = lane & 31;

    const float* adr = adst + (size_t)n * 8;
    const float ad0 = adr[0], ad1 = adr[1], ad2 = adr[2];
    const float ad3 = adr[3], ad4 = adr[4], ad5 = adr[5];

    const int start = rowptr[n];
    const int dg = deg[n];
    const char* xcb = (const char*)xp + c * 2;

    float z0 = 0.f, z1 = 0.f, z2 = 0.f, z3 = 0.f, z4 = 0.f, z5 = 0.f;
    float dl0 = 0.f, dl1 = 0.f, dl2 = 0.f, dl3 = 0.f, dl4 = 0.f, dl5 = 0.f;

    for (int base = 0; base < dg; base += 32) {
        const int rem = dg - base;
        const bool valid = el < rem;
        const int s = valid ? adj[start + base + el] : 0;
        const float4* a4 = (const float4*)(asrc + (size_t)s * 8);
        const float4 A = a4[0], Bv = a4[1];
        float v0 = A.x + ad0, v1 = A.y + ad1, v2 = A.z + ad2;
        float v3 = A.w + ad3, v4 = Bv.x + ad4, v5 = Bv.y + ad5;
        v0 = fmaxf(v0, NEG_SLOPE * v0); v1 = fmaxf(v1, NEG_SLOPE * v1);
        v2 = fmaxf(v2, NEG_SLOPE * v2); v3 = fmaxf(v3, NEG_SLOPE * v3);
        v4 = fmaxf(v4, NEG_SLOPE * v4); v5 = fmaxf(v5, NEG_SLOPE * v5);
        const float w0 = valid ? __expf(v0) : 0.f;
        const float w1 = valid ? __expf(v1) : 0.f;
        const float w2 = valid ? __expf(v2) : 0.f;
        const float w3 = valid ? __expf(v3) : 0.f;
        const float w4 = valid ? __expf(v4) : 0.f;
        const float w5 = valid ? __expf(v5) : 0.f;
        dl0 += w0; dl1 += w1; dl2 += w2; dl3 += w3; dl4 += w4; dl5 += w5;
        float4 r0, r1;
        r0.x = __int_as_float(s * 64);        // byte offset of fp16 x row
        r0.y = w0; r0.z = w1; r0.w = w2;
        r1.x = w3; r1.y = w4; r1.z = w5; r1.w = 0.f;
        if (lane < 32) { st0[wv][el] = r0; st1[wv][el] = r1; }

        // halves take even/odd edges; trip padded x4 (pad slots zero-weight)
        const int cnt = min(32, rem);
        const int nh = (((cnt + 1) >> 1) + 3) & ~3;
        for (int i = 0; i < nh; i += 4) {
            #pragma unroll
            for (int q = 0; q < 4; ++q) {
                const int idx = 2 * (i + q) + half;
                const float4 u0 = st0[wv][idx];
                const float4 u1 = st1[wv][idx];
                const float xv = __half2float(
                    *(const __half*)(xcb + __float_as_int(u0.x)));
                z0 = fmaf(u0.y, xv, z0); z1 = fmaf(u0.z, xv, z1);
                z2 = fmaf(u0.w, xv, z2); z3 = fmaf(u1.x, xv, z3);
                z4 = fmaf(u1.y, xv, z4); z5 = fmaf(u1.z, xv, z5);
            }
        }
    }
    // combine halves (even/odd edge partial sums)
    z0 += __shfl_xor(z0, 32); z1 += __shfl_xor(z1, 32);
    z2 += __shfl_xor(z2, 32); z3 += __shfl_xor(z3, 32);
    z4 += __shfl_xor(z4, 32); z5 += __shfl_xor(z5, 32);
    // denominators over the 32 edge-slots (halves identical)
    #pragma unroll
    for (int o = 1; o <= 16; o <<= 1) {
        dl0 += __shfl_xor(dl0, o); dl1 += __shfl_xor(dl1, o);
        dl2 += __shfl_xor(dl2, o); dl3 += __shfl_xor(dl3, o);
        dl4 += __shfl_xor(dl4, o); dl5 += __shfl_xor(dl5, o);
    }
    if (half == 0) {
        __half* zr = zn + (size_t)n * 192 + c;
        zr[0]   = __float2half(z0 / dl0);
        zr[32]  = __float2half(z1 / dl1);
        zr[64]  = __float2half(z2 / dl2);
        zr[96]  = __float2half(z3 / dl3);
        zr[128] = __float2half(z4 / dl4);
        zr[160] = __float2half(z5 / dl5);
    }
}

// ==================== post: y = (1/6) sum_h znorm_h . W_h + b ===============
// Block = TILE nodes, 192 threads (h = t>>5, c = t&31). W columns pre-packed
// as half2 pairs (whalf); znorm staged in LDS; half2 hfma2 dot products.
// FUSE=1: fused MLP head + sigmoid (y never hits memory).
template<int FUSE>
__global__ __launch_bounds__(192) void k_post(
    const __half* __restrict__ zn, const unsigned int* __restrict__ whalf,
    const float* __restrict__ bias, __half* __restrict__ yout,
    const int* __restrict__ user, const float* __restrict__ u_table,
    const float* __restrict__ weff, float* __restrict__ outp, int N)
{
    __shared__ unsigned int znl[TILE][96];
    __shared__ float part[TILE][192];
    const int t = threadIdx.x;
    const int h = t >> 5, c = t & 31;
    const int n0 = blockIdx.x * TILE;

    const uint4* wq = (const uint4*)(whalf + (size_t)t * 16);
    const uint4 w0 = wq[0], w1 = wq[1], w2 = wq[2], w3 = wq[3];

    {   // stage znorm tile: 16 rows x 96 dwords; thread loads 8 dwords
        const int m = t / 12, slot = t - m * 12;
        const int n = n0 + m;
        if (n < N) {
            const uint4* src = (const uint4*)((const unsigned int*)zn
                               + (size_t)n * 96 + slot * 8);
            uint4 a = src[0], b = src[1];
            uint4* d = (uint4*)&znl[m][slot * 8];
            d[0] = a; d[1] = b;
        }
    }
    __syncthreads();

    #define DOT4(W) { \
        unsigned int zz0 = zp[0], zz1 = zp[1], zz2 = zp[2], zz3 = zp[3]; \
        acc2 = __hfma2(*(__half2*)&zz0, *(__half2*)&W.x, acc2); \
        acc2 = __hfma2(*(__half2*)&zz1, *(__half2*)&W.y, acc2); \
        acc2 = __hfma2(*(__half2*)&zz2, *(__half2*)&W.z, acc2); \
        acc2 = __hfma2(*(__half2*)&zz3, *(__half2*)&W.w, acc2); zp += 4; }

    #pragma unroll 4
    for (int m = 0; m < TILE; ++m) {
        const unsigned int* zp = &znl[m][h * 16];
        __half2 acc2 = __float2half2_rn(0.f);
        DOT4(w0) DOT4(w1) DOT4(w2) DOT4(w3)
        part[m][t] = __low2float(acc2) + __high2float(acc2);
    }
    #undef DOT4
    __syncthreads();

    #pragma unroll
    for (int mb = 0; mb < 3; ++mb) {
        const int m = mb * 6 + h;             // h in 0..5 -> m in 0..17
        const int n = n0 + m;
        if (m < TILE && n < N) {
            const float y = (part[m][c] + part[m][32 + c] + part[m][64 + c]
                           + part[m][96 + c] + part[m][128 + c]
                           + part[m][160 + c]) * (1.f / 6.f) + bias[c];
            if (FUSE == 0) {
                yout[(size_t)n * 32 + c] = __float2half(y);
            } else {
                const float u = u_table[(size_t)user[n] * 32 + c];
                float p = fmaf(y, weff[32 + c], u * weff[c]);
                #pragma unroll
                for (int o = 16; o > 0; o >>= 1) p += __shfl_xor(p, o);
                if (c == 0) outp[n] = 1.f / (1.f + __expf(-(p + weff[64])));
            }
        }
    }
}

// ==================== launch ================================================

extern "C" void kernel_launch(void* const* d_in, const int* in_sizes, int n_in,
                              void* d_out, int out_size, void* d_ws, size_t ws_size,
                              hipStream_t stream)
{
    const int*   user    = (const int*)  d_in[0];
    const int*   item    = (const int*)  d_in[1];
    const int*   graph   = (const int*)  d_in[2];
    const float* u_table = (const float*)d_in[3];
    const float* i_table = (const float*)d_in[4];
    const float* W1      = (const float*)d_in[5];
    const float* a_src1  = (const float*)d_in[6];
    const float* a_dst1  = (const float*)d_in[7];
    const float* b1      = (const float*)d_in[8];
    const float* W2      = (const float*)d_in[9];
    const float* a_src2  = (const float*)d_in[10];
    const float* a_dst2  = (const float*)d_in[11];
    const float* b2      = (const float*)d_in[12];
    const float* lw1     = (const float*)d_in[13];
    const float* lb1     = (const float*)d_in[14];
    const float* lw2     = (const float*)d_in[15];
    const float* lb2     = (const float*)d_in[16];

    const int B  = in_sizes[0];
    const int N  = B;
    const int E  = in_sizes[2] / 2;
    const int Et = E + N;
    const int NBK = (N + 255) / 256;
    const int NBLK = (E + CHUNK - 1) / CHUNK;

    float* ws = (float*)d_ws;
    size_t off = 0;
    __half* xp1   = (__half*)(ws + off); off += (size_t)N * 16;  // N*32 halves
    __half* y1h   = (__half*)(ws + off); off += (size_t)N * 16;
    __half* zn    = (__half*)(ws + off); off += (size_t)N * 96;  // N*192 halves
    float* asrc   = ws + off; off += (size_t)N * 8;
    float* adst   = ws + off; off += (size_t)N * 8;
    float* wsd1   = ws + off; off += 384;
    float* wsd2   = ws + off; off += 384;
    float* weff   = ws + off; off += 128;
    unsigned int* whalf1 = (unsigned int*)(ws + off); off += 3072;
    unsigned int* whalf2 = (unsigned int*)(ws + off); off += 3072;
    int*   deg    = (int*)(ws + off); off += N;
    int*   rowptr = (int*)(ws + off); off += N;
    int*   bcnt   = (int*)(ws + off); off += NBK + 1;
    int*   boff   = (int*)(ws + off); off += NBK + 1;
    int*   bbase  = (int*)(ws + off); off += (size_t)NBLK * NBK;
    int*   adj    = (int*)(ws + off); off += Et + 2;
    off = (off + 1) & ~(size_t)1;
    int2*  pairs  = (int2*)(ws + off); off += (size_t)E * 2;

    const int ggrid = (N + 3) / 4;
    const int pgrid = (N + TILE - 1) / TILE;

    // ---- edge partition + CSR build (graph shared by both layers) ----
    hipMemsetAsync(bcnt, 0, (NBK + 1) * sizeof(int), stream);
    hipLaunchKernelGGL(k_hist, dim3(NBLK), dim3(256), 0, stream,
        graph, E, bcnt, bbase, NBK);
    hipLaunchKernelGGL(k_bucket_scan, dim3(1), dim3(256), 0, stream,
        bcnt, boff, NBK);
    hipLaunchKernelGGL(k_bin2, dim3(NBLK), dim3(256), 0, stream,
        graph, E, boff, bbase, pairs, NBK);
    hipLaunchKernelGGL(k_build, dim3(NBK), dim3(256), 0, stream,
        pairs, boff, rowptr, deg, adj, N);

    // ---- setup ----
    hipLaunchKernelGGL(k_setup, dim3(1), dim3(832), 0, stream,
        W1, a_src1, a_dst1, W2, a_src2, a_dst2,
        lw1, lb1, lw2, lb2, wsd1, wsd2, weff, whalf1, whalf2);

    // ---- GAT layer 1 ----
    hipLaunchKernelGGL(k_prep<1>, dim3(pgrid), dim3(192), 0, stream,
        i_table, (const __half*)nullptr, item, wsd1, xp1, asrc, adst, N);
    hipLaunchKernelGGL(k_gat, dim3(ggrid), dim3(256), 0, stream,
        rowptr, deg, adj, asrc, adst, xp1, zn, N);
    hipLaunchKernelGGL(k_post<0>, dim3(pgrid), dim3(192), 0, stream,
        zn, whalf1, b1, y1h,
        (const int*)nullptr, (const float*)nullptr,
        (const float*)nullptr, (float*)nullptr, N);

    // ---- GAT layer 2 + fused MLP head ----
    hipLaunchKernelGGL(k_prep<0>, dim3(pgrid), dim3(192), 0, stream,
        (const float*)nullptr, y1h, (const int*)nullptr, wsd2,
        (__half*)nullptr, asrc, adst, N);
    hipLaunchKernelGGL(k_gat, dim3(ggrid), dim3(256), 0, stream,
        rowptr, deg, adj, asrc, adst, y1h, zn, N);
    hipLaunchKernelGGL(k_post<1>, dim3(pgrid), dim3(192), 0, stream,
        zn, whalf2, b2, (__half*)nullptr,
        user, u_table, weff, (float*)d_out, N);
}

// Round 12
// 170.898 us; speedup vs baseline: 3.0476x; 1.2528x over previous
//
#include <hip/hip_runtime.h>
#include <hip/hip_fp16.h>
#include <math.h>

#define NEG_SLOPE 0.2f
#define TILE 16   // nodes per prep/post block
#define BKB2 8    // bucket = dst >> 8  (256 nodes per bucket)
#define CHUNK 16384

// ==================== init: zero bcnt + fold alphas + pack W + MLP =========
__global__ void k_init(
    const float* __restrict__ W1, const float* __restrict__ as1,
    const float* __restrict__ ad1,
    const float* __restrict__ W2, const float* __restrict__ as2,
    const float* __restrict__ ad2,
    const float* __restrict__ lw1, const float* __restrict__ lb1,
    const float* __restrict__ lw2, const float* __restrict__ lb2,
    float* __restrict__ wsd1, float* __restrict__ wsd2,
    float* __restrict__ weff,
    unsigned int* __restrict__ whalf1, unsigned int* __restrict__ whalf2,
    int* __restrict__ bcnt, int NBK)
{
    int t = threadIdx.x;                      // 832 threads
    if (t <= NBK) bcnt[t] = 0;
    if (t < 768) {
        int layer = (t >= 384);
        int r = t - layer * 384;
        int k = r / 12, j = r - k * 12;
        const float* W = layer ? W2 : W1;
        const float* a = (j < 6) ? (layer ? as2 : as1) : (layer ? ad2 : ad1);
        int h = (j < 6) ? j : j - 6;
        float acc = 0.f;
        #pragma unroll
        for (int c = 0; c < 32; ++c)
            acc = fmaf(W[k * 192 + h * 32 + c], a[h * 32 + c], acc);
        (layer ? wsd2 : wsd1)[k * 12 + j] = acc;
    } else {
        int i = t - 768;                      // 0..63
        float acc = 0.f;
        for (int o = 0; o < 64; ++o) acc += lw1[i * 64 + o] * lw2[o];
        weff[i] = acc;
        if (i == 0) {
            float b = lb2[0];
            for (int o = 0; o < 64; ++o) b += lb1[o] * lw2[o];
            weff[64] = b;
        }
    }
    if (t < 384) {
        int layer = (t >= 192);
        int col = t - layer * 192;
        const float* W = layer ? W2 : W1;
        unsigned int* dst = layer ? whalf2 : whalf1;
        #pragma unroll
        for (int i = 0; i < 16; ++i) {
            __half2 p = __floats2half2_rn(W[(2 * i) * 192 + col],
                                          W[(2 * i + 1) * 192 + col]);
            dst[col * 16 + i] = *(unsigned int*)&p;
        }
    }
}

// ==================== hist (edge buckets) + layer-1 prep, fused ============
// blocks [0,NBLK): per-chunk LDS histogram; one global atomic per
// (block,bucket) reserves a contiguous range.  blocks [NBLK, NBLK+pgrid):
// layer-1 prep: gather f32 x rows via item idx, emit fp16 rows + f32 alphas.
__global__ __launch_bounds__(256) void k_hist_prep(
    const int* __restrict__ g, int E, int* __restrict__ bcnt,
    int* __restrict__ blockbase, int NBK, int NBLK,
    const float* __restrict__ xf, const int* __restrict__ gidx,
    const float* __restrict__ wsd, __half* __restrict__ xp,
    float* __restrict__ asrc, float* __restrict__ adst, int N)
{
    __shared__ int hist[256];
    __shared__ float xs[TILE * 33];
    __shared__ int   rows[TILE];
    __shared__ float wsd_s[384];
    const int t = threadIdx.x;
    if (blockIdx.x < NBLK) {
        const int blk = blockIdx.x;
        hist[t] = 0;
        __syncthreads();
        const int base = blk * CHUNK;
        const int end = min(base + CHUNK, E);
        for (int e = base + t; e < end; e += 256)
            atomicAdd(&hist[g[E + e] >> BKB2], 1);
        __syncthreads();
        if (t < NBK) {
            int c = hist[t];
            blockbase[blk * NBK + t] = c ? atomicAdd(&bcnt[t], c) : 0;
        }
    } else {
        const int n0 = (blockIdx.x - NBLK) * TILE;
        for (int i = t; i < 384; i += 256) wsd_s[i] = wsd[i];
        if (t < TILE) {
            int n = n0 + t;
            rows[t] = (n < N) ? gidx[n] : -1;
        }
        __syncthreads();
        if (t < TILE * 8) {
            int m = t >> 3, q = t & 7;
            int r = rows[m];
            float4 v = (r >= 0) ? *(const float4*)(xf + (size_t)r * 32 + q * 4)
                                : make_float4(0.f, 0.f, 0.f, 0.f);
            float* dst = xs + m * 33 + q * 4;
            dst[0] = v.x; dst[1] = v.y; dst[2] = v.z; dst[3] = v.w;
            if (r >= 0) {
                __half2 p0 = __floats2half2_rn(v.x, v.y);
                __half2 p1 = __floats2half2_rn(v.z, v.w);
                uint2 u; u.x = *(unsigned int*)&p0; u.y = *(unsigned int*)&p1;
                *(uint2*)((unsigned int*)xp + (size_t)(n0 + m) * 16 + q * 2) = u;
            }
        }
        __syncthreads();
        if (t < 192) {
            const int m = t / 12, j = t - m * 12;
            const int n = n0 + m;
            if (n < N) {
                const float* xr = xs + m * 33;
                float a = 0.f;
                #pragma unroll
                for (int k = 0; k < 32; ++k)
                    a = fmaf(xr[k], wsd_s[k * 12 + j], a);
                if (j < 6) asrc[(size_t)n * 8 + j] = a;
                else       adst[(size_t)n * 8 + (j - 6)] = a;
            }
        }
    }
}

// in-block exclusive scan of bcnt (NBK <= 256), 256 threads
__device__ __forceinline__ int scan_excl_256(int v, int* wsum)
{
    const int t = threadIdx.x, lane = t & 63, w = t >> 6;
    int incl = v;
    #pragma unroll
    for (int off = 1; off < 64; off <<= 1) {
        int u = __shfl_up(incl, off);
        if (lane >= off) incl += u;
    }
    if (lane == 63) wsum[w] = incl;
    __syncthreads();
    int base = 0;
    for (int q = 0; q < w; ++q) base += wsum[q];
    return base + incl - v;
}

// bin: LDS cursors from (inline-scanned) bcnt + reserved blockbase; packed
// pair = (src << 8) | (dst & 255) lands in contiguous runs.
__global__ __launch_bounds__(256) void k_bin2(
    const int* __restrict__ g, int E, const int* __restrict__ bcnt,
    const int* __restrict__ blockbase, int* __restrict__ pairs, int NBK)
{
    __shared__ int cur[256];
    __shared__ int wsum[4];
    const int t = threadIdx.x, blk = blockIdx.x;
    const int v = (t < NBK) ? bcnt[t] : 0;
    const int excl = scan_excl_256(v, wsum);
    if (t < NBK) cur[t] = excl + blockbase[blk * NBK + t];
    __syncthreads();
    const int base = blk * CHUNK;
    const int end = min(base + CHUNK, E);
    for (int e = base + t; e < end; e += 256) {
        int s = g[e], d = g[E + e];
        int pos = atomicAdd(&cur[d >> BKB2], 1);
        pairs[pos] = (s << 8) | (d & 255);
    }
}

// build: one block per 256-node bucket; derive per-node counts, in-block
// scan -> rowptr/deg + self-loop, scatter adj via LDS cursors.
__global__ __launch_bounds__(256) void k_build(
    const int* __restrict__ pairs, const int* __restrict__ bcnt,
    int* __restrict__ rowptr, int* __restrict__ deg, int* __restrict__ adj,
    int N, int NBK)
{
    __shared__ int cnt[256];
    __shared__ int cur[256];
    __shared__ int wsum[4];
    __shared__ int lohi[2];
    const int b = blockIdx.x, t = threadIdx.x;
    {   // bucket range from inline scan
        const int v = (t < NBK) ? bcnt[t] : 0;
        const int excl = scan_excl_256(v, wsum);
        if (t == b) { lohi[0] = excl; lohi[1] = excl + v; }
    }
    cnt[t] = 0;
    __syncthreads();
    const int lo = lohi[0], hi = lohi[1];
    for (int i = lo + t; i < hi; i += 256)
        atomicAdd(&cnt[pairs[i] & 255], 1);
    __syncthreads();
    const int v = cnt[t];
    __syncthreads();                          // wsum reuse
    const int excl = scan_excl_256(v, wsum);
    const int node = b * 256 + t;
    const int abase = lo + b * 256;
    if (node < N) {
        const int rp = abase + excl + t;
        rowptr[node] = rp;
        deg[node] = v + 1;
        adj[rp] = node;                       // self-loop first
        cur[t] = rp + 1;
    } else cur[t] = 0;
    __syncthreads();
    for (int i = lo + t; i < hi; i += 256) {
        int p = pairs[i];
        int pos = atomicAdd(&cur[p & 255], 1);
        adj[pos] = p >> 8;
    }
}

// ==================== gather: z_h[c] = sum_e w_eh * x[src_e][c] =============
// One 64-lane wave per node; lane = channel c; halves take even/odd edges.
// Record = float4 {byte_off, w01, w23, w45 (half2)}; gather body per 2 edges:
// 1 ds_read_b128 + 1 ushort load + 1 cvt + 3 pk_fma.  z acc fp16, den f32.
// No max-subtraction (scores are O(0.1); softmax is shift-invariant).
__global__ __launch_bounds__(256) void k_gat(
    const int* __restrict__ rowptr, const int* __restrict__ deg,
    const int* __restrict__ adj,
    const float* __restrict__ asrc, const float* __restrict__ adst,
    const __half* __restrict__ xp, __half* __restrict__ zn, int N)
{
    __shared__ float4 st[4][32];
    const int wv = threadIdx.x >> 6;
    const int n = blockIdx.x * 4 + wv;
    if (n >= N) return;
    const int lane = threadIdx.x & 63;
    const int half = lane >> 5;
    const int c = lane & 31;
    const int el = lane & 31;

    const float* adr = adst + (size_t)n * 8;
    const float ad0 = adr[0], ad1 = adr[1], ad2 = adr[2];
    const float ad3 = adr[3], ad4 = adr[4], ad5 = adr[5];

    const int start = rowptr[n];
    const int dg = deg[n];
    const char* xcb = (const char*)xp + c * 2;

    __half2 acc0 = __float2half2_rn(0.f);
    __half2 acc1 = __float2half2_rn(0.f);
    __half2 acc2 = __float2half2_rn(0.f);
    float dl0 = 0.f, dl1 = 0.f, dl2 = 0.f, dl3 = 0.f, dl4 = 0.f, dl5 = 0.f;

    for (int base = 0; base < dg; base += 32) {
        const int rem = dg - base;
        const bool valid = el < rem;
        const int s = valid ? adj[start + base + el] : 0;
        const float4* a4 = (const float4*)(asrc + (size_t)s * 8);
        const float4 A = a4[0], Bv = a4[1];
        float v0 = A.x + ad0, v1 = A.y + ad1, v2 = A.z + ad2;
        float v3 = A.w + ad3, v4 = Bv.x + ad4, v5 = Bv.y + ad5;
        v0 = fmaxf(v0, NEG_SLOPE * v0); v1 = fmaxf(v1, NEG_SLOPE * v1);
        v2 = fmaxf(v2, NEG_SLOPE * v2); v3 = fmaxf(v3, NEG_SLOPE * v3);
        v4 = fmaxf(v4, NEG_SLOPE * v4); v5 = fmaxf(v5, NEG_SLOPE * v5);
        const float w0 = valid ? __expf(v0) : 0.f;
        const float w1 = valid ? __expf(v1) : 0.f;
        const float w2 = valid ? __expf(v2) : 0.f;
        const float w3 = valid ? __expf(v3) : 0.f;
        const float w4 = valid ? __expf(v4) : 0.f;
        const float w5 = valid ? __expf(v5) : 0.f;
        dl0 += w0; dl1 += w1; dl2 += w2; dl3 += w3; dl4 += w4; dl5 += w5;
        float4 rec;
        rec.x = __int_as_float(s * 64);       // byte offset of fp16 x row
        const __half2 w01 = __floats2half2_rn(w0, w1);
        const __half2 w23 = __floats2half2_rn(w2, w3);
        const __half2 w45 = __floats2half2_rn(w4, w5);
        rec.y = *(const float*)&w01;
        rec.z = *(const float*)&w23;
        rec.w = *(const float*)&w45;
        if (lane < 32) st[wv][el] = rec;

        // halves take even/odd edges; trip padded x4 (pad slots zero-weight)
        const int cnt = min(32, rem);
        const int nh = (((cnt + 1) >> 1) + 3) & ~3;
        for (int i = 0; i < nh; i += 4) {
            #pragma unroll
            for (int q = 0; q < 4; ++q) {
                const float4 r = st[wv][2 * (i + q) + half];
                const __half xval = *(const __half*)(xcb + __float_as_int(r.x));
                const __half2 xv2 = __half2half2(xval);
                acc0 = __hfma2(*(const __half2*)&r.y, xv2, acc0);
                acc1 = __hfma2(*(const __half2*)&r.z, xv2, acc1);
                acc2 = __hfma2(*(const __half2*)&r.w, xv2, acc2);
            }
        }
    }
    // combine halves (even/odd edge partial sums) on packed regs
    {
        int b0 = __shfl_xor(*(const int*)&acc0, 32);
        int b1 = __shfl_xor(*(const int*)&acc1, 32);
        int b2 = __shfl_xor(*(const int*)&acc2, 32);
        acc0 = __hadd2(acc0, *(const __half2*)&b0);
        acc1 = __hadd2(acc1, *(const __half2*)&b1);
        acc2 = __hadd2(acc2, *(const __half2*)&b2);
    }
    // denominators over the 32 edge-slots (halves identical)
    #pragma unroll
    for (int o = 1; o <= 16; o <<= 1) {
        dl0 += __shfl_xor(dl0, o); dl1 += __shfl_xor(dl1, o);
        dl2 += __shfl_xor(dl2, o); dl3 += __shfl_xor(dl3, o);
        dl4 += __shfl_xor(dl4, o); dl5 += __shfl_xor(dl5, o);
    }
    if (half == 0) {
        __half* zr = zn + (size_t)n * 192 + c;
        zr[0]   = __float2half(__low2float(acc0)  / dl0);
        zr[32]  = __float2half(__high2float(acc0) / dl1);
        zr[64]  = __float2half(__low2float(acc1)  / dl2);
        zr[96]  = __float2half(__high2float(acc1) / dl3);
        zr[128] = __float2half(__low2float(acc2)  / dl4);
        zr[160] = __float2half(__high2float(acc2) / dl5);
    }
}

// ==================== post: y = (1/6) sum_h znorm_h . W_h + b ===============
// FUSE=0: also computes next layer's alphas from y in-LDS (fused prep) and
// writes fp16 y rows.  FUSE=1: fused MLP head + sigmoid.
template<int FUSE>
__global__ __launch_bounds__(192) void k_post(
    const __half* __restrict__ zn, const unsigned int* __restrict__ whalf,
    const float* __restrict__ bias, __half* __restrict__ yout,
    const float* __restrict__ wsd,
    float* __restrict__ asrc, float* __restrict__ adst,
    const int* __restrict__ user, const float* __restrict__ u_table,
    const float* __restrict__ weff, float* __restrict__ outp, int N)
{
    __shared__ unsigned int znl[TILE][96];
    __shared__ float part[TILE][192];
    __shared__ float ys[TILE][33];
    __shared__ float wsd_s[384];
    const int t = threadIdx.x;
    const int h = t >> 5, c = t & 31;
    const int n0 = blockIdx.x * TILE;

    const uint4* wq = (const uint4*)(whalf + (size_t)t * 16);
    const uint4 w0 = wq[0], w1 = wq[1], w2 = wq[2], w3 = wq[3];
    if (FUSE == 0)
        for (int i = t; i < 384; i += 192) wsd_s[i] = wsd[i];

    {   // stage znorm tile: 16 rows x 96 dwords; thread loads 8 dwords
        const int m = t / 12, slot = t - m * 12;
        const int n = n0 + m;
        if (n < N) {
            const uint4* src = (const uint4*)((const unsigned int*)zn
                               + (size_t)n * 96 + slot * 8);
            uint4 a = src[0], b = src[1];
            uint4* d = (uint4*)&znl[m][slot * 8];
            d[0] = a; d[1] = b;
        }
    }
    __syncthreads();

    #define DOT4(W) { \
        unsigned int zz0 = zp[0], zz1 = zp[1], zz2 = zp[2], zz3 = zp[3]; \
        acc2 = __hfma2(*(__half2*)&zz0, *(__half2*)&W.x, acc2); \
        acc2 = __hfma2(*(__half2*)&zz1, *(__half2*)&W.y, acc2); \
        acc2 = __hfma2(*(__half2*)&zz2, *(__half2*)&W.z, acc2); \
        acc2 = __hfma2(*(__half2*)&zz3, *(__half2*)&W.w, acc2); zp += 4; }

    #pragma unroll 4
    for (int m = 0; m < TILE; ++m) {
        const unsigned int* zp = &znl[m][h * 16];
        __half2 acc2 = __float2half2_rn(0.f);
        DOT4(w0) DOT4(w1) DOT4(w2) DOT4(w3)
        part[m][t] = __low2float(acc2) + __high2float(acc2);
    }
    #undef DOT4
    __syncthreads();

    #pragma unroll
    for (int mb = 0; mb < 3; ++mb) {
        const int m = mb * 6 + h;             // h in 0..5 -> m in 0..17
        const int n = n0 + m;
        if (m < TILE && n < N) {
            const float y = (part[m][c] + part[m][32 + c] + part[m][64 + c]
                           + part[m][96 + c] + part[m][128 + c]
                           + part[m][160 + c]) * (1.f / 6.f) + bias[c];
            if (FUSE == 0) {
                yout[(size_t)n * 32 + c] = __float2half(y);
                ys[m][c] = y;
            } else {
                const float u = u_table[(size_t)user[n] * 32 + c];
                float p = fmaf(y, weff[32 + c], u * weff[c]);
                #pragma unroll
                for (int o = 16; o > 0; o >>= 1) p += __shfl_xor(p, o);
                if (c == 0) outp[n] = 1.f / (1.f + __expf(-(p + weff[64])));
            }
        }
    }
    if (FUSE == 0) {                          // fused next-layer alpha prep
        __syncthreads();
        const int m = t / 12, j = t - m * 12;
        const int n = n0 + m;
        if (n < N) {
            const float* yr = ys[m];
            float a = 0.f;
            #pragma unroll
            for (int k = 0; k < 32; ++k) a = fmaf(yr[k], wsd_s[k * 12 + j], a);
            if (j < 6) asrc[(size_t)n * 8 + j] = a;
            else       adst[(size_t)n * 8 + (j - 6)] = a;
        }
    }
}

// ==================== launch ================================================

extern "C" void kernel_launch(void* const* d_in, const int* in_sizes, int n_in,
                              void* d_out, int out_size, void* d_ws, size_t ws_size,
                              hipStream_t stream)
{
    const int*   user    = (const int*)  d_in[0];
    const int*   item    = (const int*)  d_in[1];
    const int*   graph   = (const int*)  d_in[2];
    const float* u_table = (const float*)d_in[3];
    const float* i_table = (const float*)d_in[4];
    const float* W1      = (const float*)d_in[5];
    const float* a_src1  = (const float*)d_in[6];
    const float* a_dst1  = (const float*)d_in[7];
    const float* b1      = (const float*)d_in[8];
    const float* W2      = (const float*)d_in[9];
    const float* a_src2  = (const float*)d_in[10];
    const float* a_dst2  = (const float*)d_in[11];
    const float* b2      = (const float*)d_in[12];
    const float* lw1     = (const float*)d_in[13];
    const float* lb1     = (const float*)d_in[14];
    const float* lw2     = (const float*)d_in[15];
    const float* lb2     = (const float*)d_in[16];

    const int B  = in_sizes[0];
    const int N  = B;
    const int E  = in_sizes[2] / 2;
    const int Et = E + N;
    const int NBK = (N + 255) / 256;
    const int NBLK = (E + CHUNK - 1) / CHUNK;

    float* ws = (float*)d_ws;
    size_t off = 0;
    __half* xp1   = (__half*)(ws + off); off += (size_t)N * 16;  // N*32 halves
    __half* y1h   = (__half*)(ws + off); off += (size_t)N * 16;
    __half* zn    = (__half*)(ws + off); off += (size_t)N * 96;  // N*192 halves
    float* asrc   = ws + off; off += (size_t)N * 8;
    float* adst   = ws + off; off += (size_t)N * 8;
    float* wsd1   = ws + off; off += 384;
    float* wsd2   = ws + off; off += 384;
    float* weff   = ws + off; off += 128;
    unsigned int* whalf1 = (unsigned int*)(ws + off); off += 3072;
    unsigned int* whalf2 = (unsigned int*)(ws + off); off += 3072;
    int*   deg    = (int*)(ws + off); off += N;
    int*   rowptr = (int*)(ws + off); off += N;
    int*   bcnt   = (int*)(ws + off); off += NBK + 1;
    int*   bbase  = (int*)(ws + off); off += (size_t)NBLK * NBK;
    int*   adj    = (int*)(ws + off); off += Et + 2;
    int*   pairs  = (int*)(ws + off); off += E;

    const int ggrid = (N + 3) / 4;
    const int pgrid = (N + TILE - 1) / TILE;

    // L1: zero bcnt + setup (wsd, whalf, weff)
    hipLaunchKernelGGL(k_init, dim3(1), dim3(832), 0, stream,
        W1, a_src1, a_dst1, W2, a_src2, a_dst2,
        lw1, lb1, lw2, lb2, wsd1, wsd2, weff, whalf1, whalf2, bcnt, NBK);
    // L2: edge histogram + layer-1 prep (independent work, one dispatch)
    hipLaunchKernelGGL(k_hist_prep, dim3(NBLK + pgrid), dim3(256), 0, stream,
        graph, E, bcnt, bbase, NBK, NBLK,
        i_table, item, wsd1, xp1, asrc, adst, N);
    // L3: bin packed pairs (inline bucket scan)
    hipLaunchKernelGGL(k_bin2, dim3(NBLK), dim3(256), 0, stream,
        graph, E, bcnt, bbase, pairs, NBK);
    // L4: per-bucket CSR build (inline bucket scan)
    hipLaunchKernelGGL(k_build, dim3(NBK), dim3(256), 0, stream,
        pairs, bcnt, rowptr, deg, adj, N, NBK);
    // L5: layer-1 gather
    hipLaunchKernelGGL(k_gat, dim3(ggrid), dim3(256), 0, stream,
        rowptr, deg, adj, asrc, adst, xp1, zn, N);
    // L6: layer-1 post + fused layer-2 alpha prep
    hipLaunchKernelGGL(k_post<0>, dim3(pgrid), dim3(192), 0, stream,
        zn, whalf1, b1, y1h, wsd2, asrc, adst,
        (const int*)nullptr, (const float*)nullptr,
        (const float*)nullptr, (float*)nullptr, N);
    // L7: layer-2 gather
    hipLaunchKernelGGL(k_gat, dim3(ggrid), dim3(256), 0, stream,
        rowptr, deg, adj, asrc, adst, y1h, zn, N);
    // L8: layer-2 post + fused MLP head + sigmoid
    hipLaunchKernelGGL(k_post<1>, dim3(pgrid), dim3(192), 0, stream,
        zn, whalf2, b2, (__half*)nullptr, (const float*)nullptr,
        (float*)nullptr, (float*)nullptr,
        user, u_table, weff, (float*)d_out, N);
}

// Round 13
// 154.659 us; speedup vs baseline: 3.3676x; 1.1050x over previous
//
#include <hip/hip_runtime.h>
#include <hip/hip_fp16.h>
#include <math.h>

#define NEG_SLOPE 0.2f
#define TILE 16   // nodes per prep/post block
#define BKB2 8    // bucket = dst >> 8  (256 nodes per bucket)
#define CHUNK 16384

// ==================== init: zero bcnt + fold alphas + pack W + MLP =========
__global__ void k_init(
    const float* __restrict__ W1, const float* __restrict__ as1,
    const float* __restrict__ ad1,
    const float* __restrict__ W2, const float* __restrict__ as2,
    const float* __restrict__ ad2,
    const float* __restrict__ lw1, const float* __restrict__ lb1,
    const float* __restrict__ lw2, const float* __restrict__ lb2,
    float* __restrict__ wsd1, float* __restrict__ wsd2,
    float* __restrict__ weff,
    unsigned int* __restrict__ whalf1, unsigned int* __restrict__ whalf2,
    int* __restrict__ bcnt, int NBK)
{
    int t = threadIdx.x;                      // 832 threads
    if (t <= NBK) bcnt[t] = 0;
    if (t < 768) {
        int layer = (t >= 384);
        int r = t - layer * 384;
        int k = r / 12, j = r - k * 12;
        const float* W = layer ? W2 : W1;
        const float* a = (j < 6) ? (layer ? as2 : as1) : (layer ? ad2 : ad1);
        int h = (j < 6) ? j : j - 6;
        float acc = 0.f;
        #pragma unroll
        for (int c = 0; c < 32; ++c)
            acc = fmaf(W[k * 192 + h * 32 + c], a[h * 32 + c], acc);
        (layer ? wsd2 : wsd1)[k * 12 + j] = acc;
    } else {
        int i = t - 768;                      // 0..63
        float acc = 0.f;
        for (int o = 0; o < 64; ++o) acc += lw1[i * 64 + o] * lw2[o];
        weff[i] = acc;
        if (i == 0) {
            float b = lb2[0];
            for (int o = 0; o < 64; ++o) b += lb1[o] * lw2[o];
            weff[64] = b;
        }
    }
    if (t < 384) {
        int layer = (t >= 192);
        int col = t - layer * 192;
        const float* W = layer ? W2 : W1;
        unsigned int* dst = layer ? whalf2 : whalf1;
        #pragma unroll
        for (int i = 0; i < 16; ++i) {
            __half2 p = __floats2half2_rn(W[(2 * i) * 192 + col],
                                          W[(2 * i + 1) * 192 + col]);
            dst[col * 16 + i] = *(unsigned int*)&p;
        }
    }
}

// ==================== hist (edge buckets) + layer-1 prep, fused ============
__global__ __launch_bounds__(256) void k_hist_prep(
    const int* __restrict__ g, int E, int* __restrict__ bcnt,
    int* __restrict__ blockbase, int NBK, int NBLK,
    const float* __restrict__ xf, const int* __restrict__ gidx,
    const float* __restrict__ wsd, __half* __restrict__ xp,
    float* __restrict__ asrc, float* __restrict__ adst, int N)
{
    __shared__ int hist[256];
    __shared__ float xs[TILE * 33];
    __shared__ int   rows[TILE];
    __shared__ float wsd_s[384];
    const int t = threadIdx.x;
    if (blockIdx.x < NBLK) {
        const int blk = blockIdx.x;
        hist[t] = 0;
        __syncthreads();
        const int base = blk * CHUNK;
        const int end = min(base + CHUNK, E);
        for (int e = base + t; e < end; e += 256)
            atomicAdd(&hist[g[E + e] >> BKB2], 1);
        __syncthreads();
        if (t < NBK) {
            int c = hist[t];
            blockbase[blk * NBK + t] = c ? atomicAdd(&bcnt[t], c) : 0;
        }
    } else {
        const int n0 = (blockIdx.x - NBLK) * TILE;
        for (int i = t; i < 384; i += 256) wsd_s[i] = wsd[i];
        if (t < TILE) {
            int n = n0 + t;
            rows[t] = (n < N) ? gidx[n] : -1;
        }
        __syncthreads();
        if (t < TILE * 8) {
            int m = t >> 3, q = t & 7;
            int r = rows[m];
            float4 v = (r >= 0) ? *(const float4*)(xf + (size_t)r * 32 + q * 4)
                                : make_float4(0.f, 0.f, 0.f, 0.f);
            float* dst = xs + m * 33 + q * 4;
            dst[0] = v.x; dst[1] = v.y; dst[2] = v.z; dst[3] = v.w;
            if (r >= 0) {
                __half2 p0 = __floats2half2_rn(v.x, v.y);
                __half2 p1 = __floats2half2_rn(v.z, v.w);
                uint2 u; u.x = *(unsigned int*)&p0; u.y = *(unsigned int*)&p1;
                *(uint2*)((unsigned int*)xp + (size_t)(n0 + m) * 16 + q * 2) = u;
            }
        }
        __syncthreads();
        if (t < 192) {
            const int m = t / 12, j = t - m * 12;
            const int n = n0 + m;
            if (n < N) {
                const float* xr = xs + m * 33;
                float a = 0.f;
                #pragma unroll
                for (int k = 0; k < 32; ++k)
                    a = fmaf(xr[k], wsd_s[k * 12 + j], a);
                if (j < 6) asrc[(size_t)n * 8 + j] = a;
                else       adst[(size_t)n * 8 + (j - 6)] = a;
            }
        }
    }
}

// in-block exclusive scan of bcnt (NBK <= 256), 256 threads
__device__ __forceinline__ int scan_excl_256(int v, int* wsum)
{
    const int t = threadIdx.x, lane = t & 63, w = t >> 6;
    int incl = v;
    #pragma unroll
    for (int off = 1; off < 64; off <<= 1) {
        int u = __shfl_up(incl, off);
        if (lane >= off) incl += u;
    }
    if (lane == 63) wsum[w] = incl;
    __syncthreads();
    int base = 0;
    for (int q = 0; q < w; ++q) base += wsum[q];
    return base + incl - v;
}

// bin: LDS cursors from (inline-scanned) bcnt + reserved blockbase
__global__ __launch_bounds__(256) void k_bin2(
    const int* __restrict__ g, int E, const int* __restrict__ bcnt,
    const int* __restrict__ blockbase, int* __restrict__ pairs, int NBK)
{
    __shared__ int cur[256];
    __shared__ int wsum[4];
    const int t = threadIdx.x, blk = blockIdx.x;
    const int v = (t < NBK) ? bcnt[t] : 0;
    const int excl = scan_excl_256(v, wsum);
    if (t < NBK) cur[t] = excl + blockbase[blk * NBK + t];
    __syncthreads();
    const int base = blk * CHUNK;
    const int end = min(base + CHUNK, E);
    for (int e = base + t; e < end; e += 256) {
        int s = g[e], d = g[E + e];
        int pos = atomicAdd(&cur[d >> BKB2], 1);
        pairs[pos] = (s << 8) | (d & 255);
    }
}

// build: one block per 256-node bucket
__global__ __launch_bounds__(256) void k_build(
    const int* __restrict__ pairs, const int* __restrict__ bcnt,
    int* __restrict__ rowptr, int* __restrict__ deg, int* __restrict__ adj,
    int N, int NBK)
{
    __shared__ int cnt[256];
    __shared__ int cur[256];
    __shared__ int wsum[4];
    __shared__ int lohi[2];
    const int b = blockIdx.x, t = threadIdx.x;
    {
        const int v = (t < NBK) ? bcnt[t] : 0;
        const int excl = scan_excl_256(v, wsum);
        if (t == b) { lohi[0] = excl; lohi[1] = excl + v; }
    }
    cnt[t] = 0;
    __syncthreads();
    const int lo = lohi[0], hi = lohi[1];
    for (int i = lo + t; i < hi; i += 256)
        atomicAdd(&cnt[pairs[i] & 255], 1);
    __syncthreads();
    const int v = cnt[t];
    __syncthreads();                          // wsum reuse
    const int excl = scan_excl_256(v, wsum);
    const int node = b * 256 + t;
    const int abase = lo + b * 256;
    if (node < N) {
        const int rp = abase + excl + t;
        rowptr[node] = rp;
        deg[node] = v + 1;
        adj[rp] = node;                       // self-loop first
        cur[t] = rp + 1;
    } else cur[t] = 0;
    __syncthreads();
    for (int i = lo + t; i < hi; i += 256) {
        int p = pairs[i];
        int pos = atomicAdd(&cur[p & 255], 1);
        adj[pos] = p >> 8;
    }
}

// ==================== gather: z_h[c] = sum_e w_eh * x[src_e][c] =============
// TWO nodes per 64-lane wave: each 32-lane half owns one node (lane = channel
// = edge slot).  Weight phase: lane computes ITS node's edge-slot weights
// (invalid slots -> zero-weight record), so no duplicated work across halves,
// no cross-half combine; denominator reduce is intra-half.  Gather body per
// wave-instr covers 2 edges (one per node): 1 ds_read_b128 + 1 ushort load +
// 3 pk_fma.  z acc fp16, den f32.  No max-subtraction (scores are O(0.1)).
__global__ __launch_bounds__(256) void k_gat(
    const int* __restrict__ rowptr, const int* __restrict__ deg,
    const int* __restrict__ adj,
    const float* __restrict__ asrc, const float* __restrict__ adst,
    const __half* __restrict__ xp, __half* __restrict__ zn, int N)
{
    __shared__ float4 st[4][2][32];
    const int wv = threadIdx.x >> 6;
    const int lane = threadIdx.x & 63;
    const int half = lane >> 5;
    const int c = lane & 31;                  // channel == edge slot
    const int n = blockIdx.x * 8 + wv * 2 + half;
    const bool nvalid = (n < N);
    const int nsafe = nvalid ? n : 0;

    const float* adr = adst + (size_t)nsafe * 8;
    const float ad0 = adr[0], ad1 = adr[1], ad2 = adr[2];
    const float ad3 = adr[3], ad4 = adr[4], ad5 = adr[5];

    const int start = rowptr[nsafe];
    const int dg = nvalid ? deg[nsafe] : 1;
    const int dgmax = max(dg, __shfl_xor(dg, 32));
    const char* xcb = (const char*)xp + c * 2;

    __half2 acc0 = __float2half2_rn(0.f);
    __half2 acc1 = __float2half2_rn(0.f);
    __half2 acc2 = __float2half2_rn(0.f);
    float dl0 = 0.f, dl1 = 0.f, dl2 = 0.f, dl3 = 0.f, dl4 = 0.f, dl5 = 0.f;

    for (int base = 0; base < dgmax; base += 32) {
        const int rem = dg - base;
        const bool valid = nvalid && (c < rem);
        const int s = valid ? adj[start + base + c] : 0;
        const float4* a4 = (const float4*)(asrc + (size_t)s * 8);
        const float4 A = a4[0], Bv = a4[1];
        float v0 = A.x + ad0, v1 = A.y + ad1, v2 = A.z + ad2;
        float v3 = A.w + ad3, v4 = Bv.x + ad4, v5 = Bv.y + ad5;
        v0 = fmaxf(v0, NEG_SLOPE * v0); v1 = fmaxf(v1, NEG_SLOPE * v1);
        v2 = fmaxf(v2, NEG_SLOPE * v2); v3 = fmaxf(v3, NEG_SLOPE * v3);
        v4 = fmaxf(v4, NEG_SLOPE * v4); v5 = fmaxf(v5, NEG_SLOPE * v5);
        const float w0 = valid ? __expf(v0) : 0.f;
        const float w1 = valid ? __expf(v1) : 0.f;
        const float w2 = valid ? __expf(v2) : 0.f;
        const float w3 = valid ? __expf(v3) : 0.f;
        const float w4 = valid ? __expf(v4) : 0.f;
        const float w5 = valid ? __expf(v5) : 0.f;
        dl0 += w0; dl1 += w1; dl2 += w2; dl3 += w3; dl4 += w4; dl5 += w5;
        float4 rec;
        rec.x = __int_as_float(s * 64);       // byte offset of fp16 x row
        const __half2 w01 = __floats2half2_rn(w0, w1);
        const __half2 w23 = __floats2half2_rn(w2, w3);
        const __half2 w45 = __floats2half2_rn(w4, w5);
        rec.y = *(const float*)&w01;
        rec.z = *(const float*)&w23;
        rec.w = *(const float*)&w45;
        st[wv][half][c] = rec;                // all 64 lanes write own slot

        // gather this chunk; trip = max over both halves, padded x4; slots
        // past a node's rem carry zero weights, so they're harmless.
        const int cntw = min(32, dgmax - base);
        const int nh = (cntw + 3) & ~3;
        for (int i = 0; i < nh; i += 4) {
            #pragma unroll
            for (int q = 0; q < 4; ++q) {
                const float4 r = st[wv][half][i + q];
                const __half xval = *(const __half*)(xcb + __float_as_int(r.x));
                const __half2 xv2 = __half2half2(xval);
                acc0 = __hfma2(*(const __half2*)&r.y, xv2, acc0);
                acc1 = __hfma2(*(const __half2*)&r.z, xv2, acc1);
                acc2 = __hfma2(*(const __half2*)&r.w, xv2, acc2);
            }
        }
    }
    // denominators over the 32 edge-slots of MY half
    #pragma unroll
    for (int o = 1; o <= 16; o <<= 1) {
        dl0 += __shfl_xor(dl0, o); dl1 += __shfl_xor(dl1, o);
        dl2 += __shfl_xor(dl2, o); dl3 += __shfl_xor(dl3, o);
        dl4 += __shfl_xor(dl4, o); dl5 += __shfl_xor(dl5, o);
    }
    if (nvalid) {
        __half* zr = zn + (size_t)n * 192 + c;
        zr[0]   = __float2half(__low2float(acc0)  / dl0);
        zr[32]  = __float2half(__high2float(acc0) / dl1);
        zr[64]  = __float2half(__low2float(acc1)  / dl2);
        zr[96]  = __float2half(__high2float(acc1) / dl3);
        zr[128] = __float2half(__low2float(acc2)  / dl4);
        zr[160] = __float2half(__high2float(acc2) / dl5);
    }
}

// ==================== post: y = (1/6) sum_h znorm_h . W_h + b ===============
// FUSE=0: also computes next layer's alphas from y in-LDS (fused prep) and
// writes fp16 y rows.  FUSE=1: fused MLP head + sigmoid.
template<int FUSE>
__global__ __launch_bounds__(192) void k_post(
    const __half* __restrict__ zn, const unsigned int* __restrict__ whalf,
    const float* __restrict__ bias, __half* __restrict__ yout,
    const float* __restrict__ wsd,
    float* __restrict__ asrc, float* __restrict__ adst,
    const int* __restrict__ user, const float* __restrict__ u_table,
    const float* __restrict__ weff, float* __restrict__ outp, int N)
{
    __shared__ unsigned int znl[TILE][96];
    __shared__ float part[TILE][192];
    __shared__ float ys[TILE][33];
    __shared__ float wsd_s[384];
    const int t = threadIdx.x;
    const int h = t >> 5, c = t & 31;
    const int n0 = blockIdx.x * TILE;

    const uint4* wq = (const uint4*)(whalf + (size_t)t * 16);
    const uint4 w0 = wq[0], w1 = wq[1], w2 = wq[2], w3 = wq[3];
    if (FUSE == 0)
        for (int i = t; i < 384; i += 192) wsd_s[i] = wsd[i];

    {   // stage znorm tile: 16 rows x 96 dwords; thread loads 8 dwords
        const int m = t / 12, slot = t - m * 12;
        const int n = n0 + m;
        if (n < N) {
            const uint4* src = (const uint4*)((const unsigned int*)zn
                               + (size_t)n * 96 + slot * 8);
            uint4 a = src[0], b = src[1];
            uint4* d = (uint4*)&znl[m][slot * 8];
            d[0] = a; d[1] = b;
        }
    }
    __syncthreads();

    #define DOT4(W) { \
        unsigned int zz0 = zp[0], zz1 = zp[1], zz2 = zp[2], zz3 = zp[3]; \
        acc2 = __hfma2(*(__half2*)&zz0, *(__half2*)&W.x, acc2); \
        acc2 = __hfma2(*(__half2*)&zz1, *(__half2*)&W.y, acc2); \
        acc2 = __hfma2(*(__half2*)&zz2, *(__half2*)&W.z, acc2); \
        acc2 = __hfma2(*(__half2*)&zz3, *(__half2*)&W.w, acc2); zp += 4; }

    #pragma unroll 4
    for (int m = 0; m < TILE; ++m) {
        const unsigned int* zp = &znl[m][h * 16];
        __half2 acc2 = __float2half2_rn(0.f);
        DOT4(w0) DOT4(w1) DOT4(w2) DOT4(w3)
        part[m][t] = __low2float(acc2) + __high2float(acc2);
    }
    #undef DOT4
    __syncthreads();

    #pragma unroll
    for (int mb = 0; mb < 3; ++mb) {
        const int m = mb * 6 + h;             // h in 0..5 -> m in 0..17
        const int n = n0 + m;
        if (m < TILE && n < N) {
            const float y = (part[m][c] + part[m][32 + c] + part[m][64 + c]
                           + part[m][96 + c] + part[m][128 + c]
                           + part[m][160 + c]) * (1.f / 6.f) + bias[c];
            if (FUSE == 0) {
                yout[(size_t)n * 32 + c] = __float2half(y);
                ys[m][c] = y;
            } else {
                const float u = u_table[(size_t)user[n] * 32 + c];
                float p = fmaf(y, weff[32 + c], u * weff[c]);
                #pragma unroll
                for (int o = 16; o > 0; o >>= 1) p += __shfl_xor(p, o);
                if (c == 0) outp[n] = 1.f / (1.f + __expf(-(p + weff[64])));
            }
        }
    }
    if (FUSE == 0) {                          // fused next-layer alpha prep
        __syncthreads();
        const int m = t / 12, j = t - m * 12;
        const int n = n0 + m;
        if (n < N) {
            const float* yr = ys[m];
            float a = 0.f;
            #pragma unroll
            for (int k = 0; k < 32; ++k) a = fmaf(yr[k], wsd_s[k * 12 + j], a);
            if (j < 6) asrc[(size_t)n * 8 + j] = a;
            else       adst[(size_t)n * 8 + (j - 6)] = a;
        }
    }
}

// ==================== launch ================================================

extern "C" void kernel_launch(void* const* d_in, const int* in_sizes, int n_in,
                              void* d_out, int out_size, void* d_ws, size_t ws_size,
                              hipStream_t stream)
{
    const int*   user    = (const int*)  d_in[0];
    const int*   item    = (const int*)  d_in[1];
    const int*   graph   = (const int*)  d_in[2];
    const float* u_table = (const float*)d_in[3];
    const float* i_table = (const float*)d_in[4];
    const float* W1      = (const float*)d_in[5];
    const float* a_src1  = (const float*)d_in[6];
    const float* a_dst1  = (const float*)d_in[7];
    const float* b1      = (const float*)d_in[8];
    const float* W2      = (const float*)d_in[9];
    const float* a_src2  = (const float*)d_in[10];
    const float* a_dst2  = (const float*)d_in[11];
    const float* b2      = (const float*)d_in[12];
    const float* lw1     = (const float*)d_in[13];
    const float* lb1     = (const float*)d_in[14];
    const float* lw2     = (const float*)d_in[15];
    const float* lb2     = (const float*)d_in[16];

    const int B  = in_sizes[0];
    const int N  = B;
    const int E  = in_sizes[2] / 2;
    const int Et = E + N;
    const int NBK = (N + 255) / 256;
    const int NBLK = (E + CHUNK - 1) / CHUNK;

    float* ws = (float*)d_ws;
    size_t off = 0;
    __half* xp1   = (__half*)(ws + off); off += (size_t)N * 16;  // N*32 halves
    __half* y1h   = (__half*)(ws + off); off += (size_t)N * 16;
    __half* zn    = (__half*)(ws + off); off += (size_t)N * 96;  // N*192 halves
    float* asrc   = ws + off; off += (size_t)N * 8;
    float* adst   = ws + off; off += (size_t)N * 8;
    float* wsd1   = ws + off; off += 384;
    float* wsd2   = ws + off; off += 384;
    float* weff   = ws + off; off += 128;
    unsigned int* whalf1 = (unsigned int*)(ws + off); off += 3072;
    unsigned int* whalf2 = (unsigned int*)(ws + off); off += 3072;
    int*   deg    = (int*)(ws + off); off += N;
    int*   rowptr = (int*)(ws + off); off += N;
    int*   bcnt   = (int*)(ws + off); off += NBK + 1;
    int*   bbase  = (int*)(ws + off); off += (size_t)NBLK * NBK;
    int*   adj    = (int*)(ws + off); off += Et + 2;
    int*   pairs  = (int*)(ws + off); off += E;

    const int ggrid = (N + 7) / 8;
    const int pgrid = (N + TILE - 1) / TILE;

    // L1: zero bcnt + setup (wsd, whalf, weff)
    hipLaunchKernelGGL(k_init, dim3(1), dim3(832), 0, stream,
        W1, a_src1, a_dst1, W2, a_src2, a_dst2,
        lw1, lb1, lw2, lb2, wsd1, wsd2, weff, whalf1, whalf2, bcnt, NBK);
    // L2: edge histogram + layer-1 prep (independent work, one dispatch)
    hipLaunchKernelGGL(k_hist_prep, dim3(NBLK + pgrid), dim3(256), 0, stream,
        graph, E, bcnt, bbase, NBK, NBLK,
        i_table, item, wsd1, xp1, asrc, adst, N);
    // L3: bin packed pairs (inline bucket scan)
    hipLaunchKernelGGL(k_bin2, dim3(NBLK), dim3(256), 0, stream,
        graph, E, bcnt, bbase, pairs, NBK);
    // L4: per-bucket CSR build (inline bucket scan)
    hipLaunchKernelGGL(k_build, dim3(NBK), dim3(256), 0, stream,
        pairs, bcnt, rowptr, deg, adj, N, NBK);
    // L5: layer-1 gather
    hipLaunchKernelGGL(k_gat, dim3(ggrid), dim3(256), 0, stream,
        rowptr, deg, adj, asrc, adst, xp1, zn, N);
    // L6: layer-1 post + fused layer-2 alpha prep
    hipLaunchKernelGGL(k_post<0>, dim3(pgrid), dim3(192), 0, stream,
        zn, whalf1, b1, y1h, wsd2, asrc, adst,
        (const int*)nullptr, (const float*)nullptr,
        (const float*)nullptr, (float*)nullptr, N);
    // L7: layer-2 gather
    hipLaunchKernelGGL(k_gat, dim3(ggrid), dim3(256), 0, stream,
        rowptr, deg, adj, asrc, adst, y1h, zn, N);
    // L8: layer-2 post + fused MLP head + sigmoid
    hipLaunchKernelGGL(k_post<1>, dim3(pgrid), dim3(192), 0, stream,
        zn, whalf2, b2, (__half*)nullptr, (const float*)nullptr,
        (float*)nullptr, (float*)nullptr,
        user, u_table, weff, (float*)d_out, N);
}